// Round 1
// 3845.499 us; speedup vs baseline: 2.0217x; 2.0217x over previous
//
#include <hip/hip_runtime.h>

// ---------- types / helpers ----------
typedef __attribute__((ext_vector_type(8))) short short8;
typedef __attribute__((ext_vector_type(4))) float f32x4;
typedef __attribute__((ext_vector_type(4))) unsigned int u32x4;

__device__ __forceinline__ float bf2f(unsigned short s) {
  unsigned int v = ((unsigned int)s) << 16; float f; __builtin_memcpy(&f, &v, 4); return f;
}
__device__ __forceinline__ unsigned short f2bf(float f) {
  unsigned int u; __builtin_memcpy(&u, &f, 4);
  u += 0x7fffu + ((u >> 16) & 1u);   // RNE (finite values only here)
  return (unsigned short)(u >> 16);
}
__device__ __forceinline__ unsigned int pack2bf(float lo, float hi) {
  return (unsigned int)f2bf(lo) | ((unsigned int)f2bf(hi) << 16);
}
__device__ __forceinline__ u32x4 pack8bf(f32x4 a, f32x4 b) {
  u32x4 r;
  r[0] = pack2bf(a[0], a[1]);
  r[1] = pack2bf(a[2], a[3]);
  r[2] = pack2bf(b[0], b[1]);
  r[3] = pack2bf(b[2], b[3]);
  return r;
}
__device__ __forceinline__ void ld8bf(const unsigned short* p, float* o) {
  short8 v = *(const short8*)p;
#pragma unroll
  for (int q = 0; q < 8; ++q) o[q] = bf2f((unsigned short)v[q]);
}

// ---------- constants ----------
#define LSEQ   4096
#define DMODEL 2048
#define DINNER 4096
#define NHEADS 64
#define PROJ_N 4416    // D_INNER + NHEADS + 2*D_STATE

// ---------- bf16 MFMA GEMM:  C[m][n] = sum_k A[m][k] * B[n][k] ----------
template <bool A_F32, bool OUT_BF16>
__global__ __launch_bounds__(256) void gemm_nt(
    const void* __restrict__ Ap,
    const float* __restrict__ B,
    void* __restrict__ Cp, int K, int ldc, int nmax) {
  __shared__ __attribute__((aligned(16))) unsigned short Asm[128 * 32];
  __shared__ __attribute__((aligned(16))) unsigned short Bsm[128 * 32];
  const int tid = threadIdx.x;
  const int m0 = blockIdx.y * 128;
  const int n0 = blockIdx.x * 128;
  const int wave = tid >> 6, lane = tid & 63;
  const int wm = (wave >> 1) * 64, wn = (wave & 1) * 64;
  const int quad = lane >> 4, l16 = lane & 15;
  const int rowL = tid >> 2;
  const int kk = (tid & 3) * 8;
  const long lK = K;

  int rb0 = n0 + rowL;      if (rb0 > nmax - 1) rb0 = nmax - 1;
  int rb1 = n0 + rowL + 64; if (rb1 > nmax - 1) rb1 = nmax - 1;

  f32x4 zero = {0.f, 0.f, 0.f, 0.f};
  f32x4 acc[4][4];
#pragma unroll
  for (int i = 0; i < 4; ++i)
#pragma unroll
    for (int j = 0; j < 4; ++j) acc[i][j] = zero;

  for (int kt = 0; kt < K; kt += 32) {
    const float* pb0 = B + (long)rb0 * lK + kt + kk;
    const float* pb1 = B + (long)rb1 * lK + kt + kk;
    f32x4 b00 = *(const f32x4*)pb0;
    f32x4 b01 = *(const f32x4*)(pb0 + 4);
    f32x4 b10 = *(const f32x4*)pb1;
    f32x4 b11 = *(const f32x4*)(pb1 + 4);
    u32x4 bw0 = pack8bf(b00, b01);
    u32x4 bw1 = pack8bf(b10, b11);
    u32x4 aw0, aw1;
    if (A_F32) {
      const float* pa = (const float*)Ap + (long)(m0 + rowL) * lK + kt + kk;
      f32x4 a00 = *(const f32x4*)pa;
      f32x4 a01 = *(const f32x4*)(pa + 4);
      f32x4 a10 = *(const f32x4*)(pa + 64 * lK);
      f32x4 a11 = *(const f32x4*)(pa + 64 * lK + 4);
      aw0 = pack8bf(a00, a01);
      aw1 = pack8bf(a10, a11);
    } else {
      const unsigned short* pa = (const unsigned short*)Ap + (long)(m0 + rowL) * lK + kt + kk;
      aw0 = *(const u32x4*)pa;
      aw1 = *(const u32x4*)(pa + 64 * lK);
    }
    *(u32x4*)(Asm + tid * 8) = aw0;
    *(u32x4*)(Asm + tid * 8 + 2048) = aw1;
    *(u32x4*)(Bsm + tid * 8) = bw0;
    *(u32x4*)(Bsm + tid * 8 + 2048) = bw1;
    __syncthreads();
    short8 af[4], bfv[4];
#pragma unroll
    for (int i = 0; i < 4; ++i) {
      af[i]  = *(const short8*)(Asm + (wm + i * 16 + l16) * 32 + quad * 8);
      bfv[i] = *(const short8*)(Bsm + (wn + i * 16 + l16) * 32 + quad * 8);
    }
#pragma unroll
    for (int i = 0; i < 4; ++i)
#pragma unroll
      for (int j = 0; j < 4; ++j)
        acc[i][j] = __builtin_amdgcn_mfma_f32_16x16x32_bf16(af[i], bfv[j], acc[i][j], 0, 0, 0);
    __syncthreads();
  }

#pragma unroll
  for (int i = 0; i < 4; ++i) {
    const int mbase = m0 + wm + i * 16 + quad * 4;
#pragma unroll
    for (int j = 0; j < 4; ++j) {
      const int n = n0 + wn + j * 16 + l16;
      if (n < nmax) {
#pragma unroll
        for (int r = 0; r < 4; ++r) {
          const long o = (long)(mbase + r) * ldc + n;
          if (OUT_BF16) ((unsigned short*)Cp)[o] = f2bf(acc[i][j][r]);
          else          ((float*)Cp)[o] = acc[i][j][r];
        }
      }
    }
  }
}

// ---------- depthwise causal conv (taps=4) + bias + silu (bf16 in/out) ----------
__global__ void conv_silu_kernel(const unsigned short* __restrict__ xin,
                                 const float* __restrict__ cw,
                                 const float* __restrict__ cb,
                                 unsigned short* __restrict__ xout, long n) {
  long idx = (long)blockIdx.x * blockDim.x + threadIdx.x; // rows*4096
  if (idx >= n) return;
  int ch = (int)(idx & 4095);
  long row = idx >> 12;
  int l = (int)(row & (LSEQ - 1));
  float acc = cb[ch];
#pragma unroll
  for (int t = 0; t < 4; ++t) {
    int ll = l - 3 + t;
    float xv = (ll >= 0) ? bf2f(xin[(row - 3 + t) * 4096 + ch]) : 0.f;
    acc += xv * cw[ch * 4 + t];
  }
  acc = acc / (1.f + expf(-acc));
  xout[idx] = f2bf(acc);
}

// ---------- dt: softplus(dt_in @ dtW^T + dtb) -> fp32 ----------
__global__ void dt_kernel(const unsigned short* __restrict__ proj,
                          const float* __restrict__ dtw,
                          const float* __restrict__ dtb,
                          float* __restrict__ dt, long n) {
  long idx = (long)blockIdx.x * blockDim.x + threadIdx.x; // rows*64
  if (idx >= n) return;
  int h = (int)(idx & 63);
  long row = idx >> 6;
  const unsigned short* p = proj + row * PROJ_N + DINNER;
  float s = dtb[h];
#pragma unroll 8
  for (int k = 0; k < 64; ++k) s += bf2f(p[k]) * dtw[h * 64 + k];
  dt[idx] = (s > 20.f) ? s : log1pf(expf(s));
}

// ==================================================================
// NEW parallel chunked SSD (3 kernels)
// states layout: states[(gc*64 + h)*8192 + p*128 + n], gc = b*64 + c
// ==================================================================

// ---- phase 1: per-chunk states S_c[p][n] = sum_j dt_j*exp(cs63-cs_j)*X[j][p]*B[j][n]
__global__ __launch_bounds__(256) void ssd_states_kernel(
    const unsigned short* __restrict__ proj,
    const float* __restrict__ dtbuf,
    const float* __restrict__ A_log,
    float* __restrict__ states,
    float* __restrict__ chdec) {
  __shared__ float Bs[64][132];
  __shared__ float Xw[64][68];
  __shared__ float csh[64];
  __shared__ float dth[64];
  const int tid = threadIdx.x;
  const int gc = blockIdx.x;       // b*64 + c  (rows are contiguous: row = gc*64 + j)
  const int h  = blockIdx.y;
  const long rowbase = (long)gc * 64;

  const float negA = -expf(A_log[h]);
  if (tid < 64) {
    float d = dtbuf[(rowbase + tid) * 64 + h];
    float v = negA * d;
#pragma unroll
    for (int off = 1; off < 64; off <<= 1) {
      float t = __shfl_up(v, off);
      if (tid >= off) v += t;
    }
    csh[tid] = v;
    dth[tid] = d;
  }
  __syncthreads();
  const float cs63 = csh[63];

  // stage B (fp32, padded) and Xw = dt_j * exp(cs63-cs_j) * X[j][p]
  for (int idx = tid; idx < 64 * 16; idx += 256) {
    int r = idx >> 4, c8 = idx & 15;
    float f[8];
    ld8bf(proj + (rowbase + r) * PROJ_N + 4160 + c8 * 8, f);
#pragma unroll
    for (int q = 0; q < 8; ++q) Bs[r][c8 * 8 + q] = f[q];
  }
  for (int idx = tid; idx < 64 * 8; idx += 256) {
    int r = idx >> 3, c8 = idx & 7;
    float f[8];
    ld8bf(proj + (rowbase + r) * PROJ_N + h * 64 + c8 * 8, f);
    float w = dth[r] * expf(cs63 - csh[r]);
#pragma unroll
    for (int q = 0; q < 8; ++q) Xw[r][c8 * 8 + q] = w * f[q];
  }
  __syncthreads();

  const int p0 = (tid >> 4) * 4;       // 16 p-groups * 4 = 64
  const int n0 = (tid & 15) * 4;       // n in {n0..n0+3} u {n0+64..n0+67}
  float a0[4][4] = {};
  float a1[4][4] = {};
  for (int j = 0; j < 64; ++j) {
    f32x4 xv = *(const f32x4*)&Xw[j][p0];
    f32x4 b0 = *(const f32x4*)&Bs[j][n0];
    f32x4 b1 = *(const f32x4*)&Bs[j][n0 + 64];
#pragma unroll
    for (int pp = 0; pp < 4; ++pp)
#pragma unroll
      for (int q = 0; q < 4; ++q) {
        a0[pp][q] += xv[pp] * b0[q];
        a1[pp][q] += xv[pp] * b1[q];
      }
  }
  float* sb = states + ((long)gc * 64 + h) * 8192;
#pragma unroll
  for (int pp = 0; pp < 4; ++pp) {
    f32x4 t0, t1;
#pragma unroll
    for (int q = 0; q < 4; ++q) { t0[q] = a0[pp][q]; t1[q] = a1[pp][q]; }
    *(f32x4*)(sb + (p0 + pp) * 128 + n0) = t0;
    *(f32x4*)(sb + (p0 + pp) * 128 + n0 + 64) = t1;
  }
  if (tid == 0) chdec[gc * 64 + h] = expf(cs63);
}

// ---- phase 2: in-place exclusive prefix scan over chunks:
//      P_0 = 0 ; slot c <- P_c ; P_{c+1} = dec_c * P_c + S_c
__global__ __launch_bounds__(256) void ssd_scan_kernel(
    float* __restrict__ states, const float* __restrict__ chdec) {
  const int by = blockIdx.y;            // b*64 + h
  const int b = by >> 6, h = by & 63;
  const int pn = blockIdx.x * 256 + threadIdx.x;   // 0..8191
  float P = 0.f;
  long base = ((long)b * 64 * 64 + h) * 8192 + pn;
  for (int c = 0; c < 64; ++c) {
    long o = base + (long)c * (64 * 8192);
    float S = states[o];
    states[o] = P;
    P = chdec[(b * 64 + c) * 64 + h] * P + S;
  }
}

// ---- phase 3: Y = Sc @ Xdt + exp(cs_i) * (C @ P^T), + D-residual, * silu(z), in place
// block = (gc, head-group of 16), 512 threads. D[i][j]=C_i.B_j shared across heads.
__global__ __launch_bounds__(512) void ssd_ydo_gate_kernel(
    const unsigned short* __restrict__ proj,
    const float* __restrict__ dtbuf,
    const float* __restrict__ A_log,
    const float* __restrict__ Dv,
    const float* __restrict__ states,
    unsigned short* __restrict__ zio) {
  __shared__ unsigned short Bsb[64][136];
  __shared__ unsigned short Csb[64][136];
  __shared__ float Dm[64][68];
  __shared__ float Scm[64][68];
  __shared__ float Xw[64][68];
  __shared__ float Pt[128][68];    // transposed state: Pt[n][p]
  __shared__ float csh[64];
  __shared__ float dth[64];
  const int tid = threadIdx.x;
  const int gc = blockIdx.x;
  const int hbase = blockIdx.y * 16;
  const long rowbase = (long)gc * 64;

  // stage B, C (bf16)
  for (int idx = tid; idx < 64 * 16; idx += 512) {
    int r = idx >> 4, c8 = idx & 15;
    const unsigned short* rp = proj + (rowbase + r) * PROJ_N;
    *(short8*)&Bsb[r][c8 * 8] = *(const short8*)(rp + 4160 + c8 * 8);
    *(short8*)&Csb[r][c8 * 8] = *(const short8*)(rp + 4288 + c8 * 8);
  }
  __syncthreads();

  // D[i][j] = C_i . B_j  (head-independent since NGROUPS=1)
  {
    const int i0 = (tid >> 4) * 2;
    const int j0 = (tid & 15) * 4;
    float a[2][4] = {};
    for (int n8 = 0; n8 < 128; n8 += 8) {
      float c0[8], c1[8], b0[8], b1[8], b2[8], b3[8];
      ld8bf(&Csb[i0][n8], c0);     ld8bf(&Csb[i0 + 1][n8], c1);
      ld8bf(&Bsb[j0][n8], b0);     ld8bf(&Bsb[j0 + 1][n8], b1);
      ld8bf(&Bsb[j0 + 2][n8], b2); ld8bf(&Bsb[j0 + 3][n8], b3);
#pragma unroll
      for (int q = 0; q < 8; ++q) {
        a[0][0] += c0[q] * b0[q]; a[0][1] += c0[q] * b1[q];
        a[0][2] += c0[q] * b2[q]; a[0][3] += c0[q] * b3[q];
        a[1][0] += c1[q] * b0[q]; a[1][1] += c1[q] * b1[q];
        a[1][2] += c1[q] * b2[q]; a[1][3] += c1[q] * b3[q];
      }
    }
    f32x4 t0, t1;
#pragma unroll
    for (int q = 0; q < 4; ++q) { t0[q] = a[0][q]; t1[q] = a[1][q]; }
    *(f32x4*)&Dm[i0][j0] = t0;
    *(f32x4*)&Dm[i0 + 1][j0] = t1;
  }
  // (first per-head __syncthreads orders these stores before any Dm read)

  const int ig = tid >> 4;          // 0..31
  const int i0 = ig * 2;
  const int p0 = (tid & 15) * 4;
  const int prow = tid & 63;        // Pt loader: p row
  const int nc0 = (tid >> 6) * 16;  // Pt loader: n window (wave-uniform)

  for (int hh = 0; hh < 16; ++hh) {
    const int h = hbase + hh;
    const float Dh = Dv[h];
    // issue state loads early (one full 64B line per thread)
    const float* sb = states + ((long)gc * 64 + h) * 8192;
    f32x4 pv0 = *(const f32x4*)(sb + prow * 128 + nc0);
    f32x4 pv1 = *(const f32x4*)(sb + prow * 128 + nc0 + 4);
    f32x4 pv2 = *(const f32x4*)(sb + prow * 128 + nc0 + 8);
    f32x4 pv3 = *(const f32x4*)(sb + prow * 128 + nc0 + 12);

    const float negA = -expf(A_log[h]);
    if (tid < 64) {
      float d = dtbuf[(rowbase + tid) * 64 + h];
      float v = negA * d;
#pragma unroll
      for (int off = 1; off < 64; off <<= 1) {
        float t = __shfl_up(v, off);
        if (tid >= off) v += t;
      }
      csh[tid] = v;
      dth[tid] = d;
    }
    __syncthreads();   // csh/dth ready; also fences prev head's reads of Xw/Pt/Scm

    // Xw[j][p] = dt_j * X[j][p]
    {
      const int r = tid >> 3, c8 = tid & 7;
      float f[8];
      ld8bf(proj + (rowbase + r) * PROJ_N + h * 64 + c8 * 8, f);
      const float d = dth[r];
#pragma unroll
      for (int q = 0; q < 8; ++q) Xw[r][c8 * 8 + q] = d * f[q];
    }
    // Pt[n][p] <- state (transpose in LDS; wave-uniform n => conflict-free writes)
    {
#pragma unroll
      for (int q = 0; q < 4; ++q) Pt[nc0 + q][prow] = pv0[q];
#pragma unroll
      for (int q = 0; q < 4; ++q) Pt[nc0 + 4 + q][prow] = pv1[q];
#pragma unroll
      for (int q = 0; q < 4; ++q) Pt[nc0 + 8 + q][prow] = pv2[q];
#pragma unroll
      for (int q = 0; q < 4; ++q) Pt[nc0 + 12 + q][prow] = pv3[q];
    }
    // Scm[i][j] = D[i][j] * exp(cs_i - cs_j), j<=i else 0
    {
      const int i = tid >> 3;
      const int j0 = (tid & 7) * 8;
      const float ci = csh[i];
      f32x4 d0 = *(const f32x4*)&Dm[i][j0];
      f32x4 d1 = *(const f32x4*)&Dm[i][j0 + 4];
      f32x4 s0, s1;
#pragma unroll
      for (int q = 0; q < 4; ++q) {
        int j = j0 + q;
        s0[q] = (j <= i) ? d0[q] * expf(ci - csh[j]) : 0.f;
        j = j0 + 4 + q;
        s1[q] = (j <= i) ? d1[q] * expf(ci - csh[j]) : 0.f;
      }
      *(f32x4*)&Scm[i][j0] = s0;
      *(f32x4*)&Scm[i][j0 + 4] = s1;
    }
    __syncthreads();   // Xw, Pt, Scm ready

    // Y_diag: ya[i][p] = sum_j Scm[i][j] * Xw[j][p]
    float ya[2][4] = {};
    for (int j = 0; j < 64; ++j) {
      float s0 = Scm[i0][j], s1 = Scm[i0 + 1][j];
      f32x4 xv = *(const f32x4*)&Xw[j][p0];
#pragma unroll
      for (int q = 0; q < 4; ++q) {
        ya[0][q] += s0 * xv[q];
        ya[1][q] += s1 * xv[q];
      }
    }
    // Y_off: yb[i][p] = sum_n C[i][n] * P[p][n]
    float yb[2][4] = {};
    for (int n8 = 0; n8 < 128; n8 += 8) {
      float c0[8], c1[8];
      ld8bf(&Csb[i0][n8], c0);
      ld8bf(&Csb[i0 + 1][n8], c1);
#pragma unroll
      for (int q = 0; q < 8; ++q) {
        f32x4 pvv = *(const f32x4*)&Pt[n8 + q][p0];
#pragma unroll
        for (int k = 0; k < 4; ++k) {
          yb[0][k] += c0[q] * pvv[k];
          yb[1][k] += c1[q] * pvv[k];
        }
      }
    }
    // gate + write in place
    const float e0 = expf(csh[i0]), e1 = expf(csh[i0 + 1]);
#pragma unroll
    for (int ii = 0; ii < 2; ++ii) {
      const long r = rowbase + i0 + ii;
      const long zo = r * 4096 + h * 64 + p0;
      const unsigned short* xr = proj + r * PROJ_N + h * 64 + p0;
      const float e = ii ? e1 : e0;
#pragma unroll
      for (int k = 0; k < 4; ++k) {
        float y = ya[ii][k] + e * yb[ii][k];
        float xraw = bf2f(xr[k]);
        float zz = bf2f(zio[zo + k]);
        float sz = zz / (1.f + expf(-zz));
        zio[zo + k] = f2bf((y + xraw * Dh) * sz);
      }
    }
    __syncthreads();   // protect shared buffers before next head
  }
}

// ---------- OLD serial SSD (fallback when workspace too small) ----------
__global__ __launch_bounds__(512) void ssd_gate_kernel(
    const unsigned short* __restrict__ proj,
    const float* __restrict__ dtbuf,
    const float* __restrict__ A_log,
    const float* __restrict__ Dv,
    unsigned short* __restrict__ zio) {
  __shared__ float st[64][128];
  __shared__ float Bs[64][128];
  __shared__ float Cs[64][128];
  __shared__ float Xs[64][64];
  __shared__ float Sc[64][64];
  __shared__ float cs[64];
  __shared__ float dtc[64];

  const int tid = threadIdx.x;
  const int bl = blockIdx.x >> 6;
  const int h = blockIdx.x & 63;
  const float negA = -expf(A_log[h]);
  const float Dh = Dv[h];

  for (int i = tid; i < 64 * 128; i += 512) (&st[0][0])[i] = 0.f;

  for (int c = 0; c < 64; ++c) {
    const long rowbase = (long)bl * LSEQ + c * 64;
    if (tid < 64) dtc[tid] = dtbuf[(rowbase + tid) * 64 + h];
    __syncthreads();
    if (tid == 0) {
      float run = 0.f;
      for (int j = 0; j < 64; ++j) { run += negA * dtc[j]; cs[j] = run; }
    }
    {
      const int j = tid >> 3;
      const int c8 = tid & 7;
      const unsigned short* rp = proj + (rowbase + j) * PROJ_N;
      const float dj = dtc[j];
#pragma unroll
      for (int q = 0; q < 8; ++q)
        Xs[j][c8 * 8 + q] = bf2f(rp[h * 64 + c8 * 8 + q]) * dj;
#pragma unroll
      for (int q = 0; q < 16; ++q) {
        Bs[j][c8 * 16 + q] = bf2f(rp[4160 + c8 * 16 + q]);
        Cs[j][c8 * 16 + q] = bf2f(rp[4288 + c8 * 16 + q]);
      }
    }
    __syncthreads();
    {
      const int i0 = (tid >> 4) * 2;
      const int j0 = (tid & 15) * 4;
      float a[2][4] = {};
      for (int n = 0; n < 128; ++n) {
        float c0 = Cs[i0][n], c1 = Cs[i0 + 1][n];
        float b0 = Bs[j0][n], b1 = Bs[j0 + 1][n], b2 = Bs[j0 + 2][n], b3 = Bs[j0 + 3][n];
        a[0][0] += c0 * b0; a[0][1] += c0 * b1; a[0][2] += c0 * b2; a[0][3] += c0 * b3;
        a[1][0] += c1 * b0; a[1][1] += c1 * b1; a[1][2] += c1 * b2; a[1][3] += c1 * b3;
      }
#pragma unroll
      for (int ii = 0; ii < 2; ++ii)
#pragma unroll
        for (int jj = 0; jj < 4; ++jj) {
          int i = i0 + ii, j = j0 + jj;
          Sc[i][j] = (j <= i) ? a[ii][jj] * expf(cs[i] - cs[j]) : 0.f;
        }
    }
    __syncthreads();
    {
      const int i0 = (tid >> 4) * 2;
      const int p0 = (tid & 15) * 4;
      float a1[2][4] = {};
      for (int j = 0; j < 64; ++j) {
        float s0 = Sc[i0][j], s1 = Sc[i0 + 1][j];
        float x0 = Xs[j][p0], x1 = Xs[j][p0 + 1], x2 = Xs[j][p0 + 2], x3 = Xs[j][p0 + 3];
        a1[0][0] += s0 * x0; a1[0][1] += s0 * x1; a1[0][2] += s0 * x2; a1[0][3] += s0 * x3;
        a1[1][0] += s1 * x0; a1[1][1] += s1 * x1; a1[1][2] += s1 * x2; a1[1][3] += s1 * x3;
      }
      float a2[2][4] = {};
      for (int n = 0; n < 128; ++n) {
        float c0 = Cs[i0][n], c1 = Cs[i0 + 1][n];
        float t0 = st[p0][n], t1 = st[p0 + 1][n], t2 = st[p0 + 2][n], t3 = st[p0 + 3][n];
        a2[0][0] += c0 * t0; a2[0][1] += c0 * t1; a2[0][2] += c0 * t2; a2[0][3] += c0 * t3;
        a2[1][0] += c1 * t0; a2[1][1] += c1 * t1; a2[1][2] += c1 * t2; a2[1][3] += c1 * t3;
      }
      float e0 = expf(cs[i0]), e1 = expf(cs[i0 + 1]);
#pragma unroll
      for (int ii = 0; ii < 2; ++ii) {
        const long r = rowbase + i0 + ii;
        const long zo = r * 4096 + h * 64 + p0;
        const unsigned short* xr = proj + r * PROJ_N + h * 64 + p0;
        float e = ii ? e1 : e0;
#pragma unroll
        for (int pp = 0; pp < 4; ++pp) {
          float y = a1[ii][pp] + e * a2[ii][pp];
          float xraw = bf2f(xr[pp]);
          float zz = bf2f(zio[zo + pp]);
          float sz = zz / (1.f + expf(-zz));
          zio[zo + pp] = f2bf((y + xraw * Dh) * sz);
        }
      }
    }
    __syncthreads();
    {
      const int j = tid >> 3;
      const int p0 = (tid & 7) * 8;
      float f = expf(cs[63] - cs[j]);
#pragma unroll
      for (int q = 0; q < 8; ++q) Xs[j][p0 + q] *= f;
    }
    __syncthreads();
    {
      const float dec = expf(cs[63]);
      const int p0 = (tid >> 5) * 4;
      const int n0 = (tid & 31) * 4;
      float a[4][4] = {};
      for (int j = 0; j < 64; ++j) {
        float x0 = Xs[j][p0], x1 = Xs[j][p0 + 1], x2 = Xs[j][p0 + 2], x3 = Xs[j][p0 + 3];
        float b0 = Bs[j][n0], b1 = Bs[j][n0 + 1], b2 = Bs[j][n0 + 2], b3 = Bs[j][n0 + 3];
        a[0][0] += x0 * b0; a[0][1] += x0 * b1; a[0][2] += x0 * b2; a[0][3] += x0 * b3;
        a[1][0] += x1 * b0; a[1][1] += x1 * b1; a[1][2] += x1 * b2; a[1][3] += x1 * b3;
        a[2][0] += x2 * b0; a[2][1] += x2 * b1; a[2][2] += x2 * b2; a[2][3] += x2 * b3;
        a[3][0] += x3 * b0; a[3][1] += x3 * b1; a[3][2] += x3 * b2; a[3][3] += x3 * b3;
      }
#pragma unroll
      for (int pp = 0; pp < 4; ++pp)
#pragma unroll
        for (int nn = 0; nn < 4; ++nn)
          st[p0 + pp][n0 + nn] = dec * st[p0 + pp][n0 + nn] + a[pp][nn];
    }
    __syncthreads();
  }
}

// ---------- launch ----------
extern "C" void kernel_launch(void* const* d_in, const int* in_sizes, int n_in,
                              void* d_out, int out_size, void* d_ws, size_t ws_size,
                              hipStream_t stream) {
  (void)in_sizes; (void)n_in; (void)out_size;
  const float* x    = (const float*)d_in[0];
  const float* w1   = (const float*)d_in[1]; // 8192 x 2048
  const float* cw   = (const float*)d_in[2]; // 4096 x 4
  const float* cb   = (const float*)d_in[3]; // 4096
  const float* w2   = (const float*)d_in[4]; // 4416 x 4096
  const float* dtw  = (const float*)d_in[5]; // 64 x 64
  const float* dtb  = (const float*)d_in[6]; // 64
  const float* Alog = (const float*)d_in[7]; // 64
  const float* Dv   = (const float*)d_in[8]; // 64
  const float* w3   = (const float*)d_in[9]; // 2048 x 4096
  float* out = (float*)d_out;

  // per-pass scratch: S1 (xc/z) + S2 (proj) + dtf + [chdec + states] (new path)
  // need(CR) = CR*8192 + CR*8832 + CR*256 + nb*16384 + nb*134217728, nb = CR/4096
  const size_t NEED8 = 410025984ull;   // CR=8192 new path
  const size_t NEED4 = 205012992ull;   // CR=4096 new path
  int CR; bool newpath;
  if      (ws_size >= NEED8)               { CR = 8192; newpath = true;  }
  else if (ws_size >= NEED4)               { CR = 4096; newpath = true;  }
  else if (ws_size >= (size_t)8192 * 17280){ CR = 8192; newpath = false; }
  else if (ws_size >= (size_t)4096 * 17280){ CR = 4096; newpath = false; }
  else return;  // diagnostic: error == 8.69e-2 means ws too small

  char* w = (char*)d_ws;
  const size_t S1 = (size_t)CR * 4096 * 2;
  const size_t S2 = (size_t)CR * PROJ_N * 2;
  const int nb = CR / LSEQ;
  unsigned short* xc   = (unsigned short*)(w);       // conv out   [0, S1)
  unsigned short* xp   = (unsigned short*)(w + S1);  // pre-conv   (inside proj region)
  unsigned short* proj = (unsigned short*)(w + S1);  // x_proj out — over xp (dead)
  unsigned short* z    = (unsigned short*)(w);       // z branch — over xc (dead)
  float* dtf           = (float*)(w + S1 + S2);
  float* chdec         = (float*)(w + S1 + S2 + (size_t)CR * 256);
  float* states        = (float*)(w + S1 + S2 + (size_t)CR * 256 + (size_t)nb * 16384);

  for (int r0 = 0; r0 < 8192; r0 += CR) {
    const float* xr = x + (size_t)r0 * DMODEL;
    // 1) in_proj x-half -> xp (A fp32, out bf16)
    dim3 g1(DINNER / 128, CR / 128);
    gemm_nt<true, true><<<g1, 256, 0, stream>>>(xr, w1, xp, DMODEL, DINNER, DINNER);
    // 2) conv + silu -> xc
    conv_silu_kernel<<<((long)CR * DINNER) / 256, 256, 0, stream>>>(xp, cw, cb, xc, (long)CR * DINNER);
    // 3) x_proj -> proj (A bf16, out bf16; overwrites xp region)
    dim3 g2((PROJ_N + 127) / 128, CR / 128);
    gemm_nt<false, true><<<g2, 256, 0, stream>>>(xc, w2, proj, DINNER, PROJ_N, PROJ_N);
    // 4) dt
    dt_kernel<<<((long)CR * NHEADS) / 256, 256, 0, stream>>>(proj, dtw, dtb, dtf, (long)CR * NHEADS);
    // 5) in_proj z-half -> z (A fp32, out bf16; overwrites xc region)
    gemm_nt<true, true><<<g1, 256, 0, stream>>>(xr, w1 + (size_t)DINNER * DMODEL, z, DMODEL, DINNER, DINNER);
    // 6) SSD + gate, in place over z
    if (newpath) {
      ssd_states_kernel<<<dim3(nb * 64, 64), 256, 0, stream>>>(proj, dtf, Alog, states, chdec);
      ssd_scan_kernel<<<dim3(32, nb * 64), 256, 0, stream>>>(states, chdec);
      ssd_ydo_gate_kernel<<<dim3(nb * 64, 4), 512, 0, stream>>>(proj, dtf, Alog, Dv, states, z);
    } else {
      ssd_gate_kernel<<<(CR / LSEQ) * NHEADS, 512, 0, stream>>>(proj, dtf, Alog, Dv, z);
    }
    // 7) out_proj -> d_out (A bf16, out fp32)
    dim3 g3(DMODEL / 128, CR / 128);
    gemm_nt<false, false><<<g3, 256, 0, stream>>>(z, w3, out + (size_t)r0 * DMODEL, DINNER, DMODEL, DMODEL);
  }
}

// Round 3
// 2650.693 us; speedup vs baseline: 2.9330x; 1.4508x over previous
//
#include <hip/hip_runtime.h>

// ---------- types / helpers ----------
typedef __attribute__((ext_vector_type(8))) short short8;
typedef __attribute__((ext_vector_type(4))) short s16x4;
typedef __attribute__((ext_vector_type(4))) float f32x4;
typedef __attribute__((ext_vector_type(4))) unsigned int u32x4;

__device__ __forceinline__ float bf2f(unsigned short s) {
  unsigned int v = ((unsigned int)s) << 16; float f; __builtin_memcpy(&f, &v, 4); return f;
}
__device__ __forceinline__ unsigned short f2bf(float f) {
  unsigned int u; __builtin_memcpy(&u, &f, 4);
  u += 0x7fffu + ((u >> 16) & 1u);   // RNE (finite values only here)
  return (unsigned short)(u >> 16);
}
__device__ __forceinline__ unsigned int pack2bf(float lo, float hi) {
  return (unsigned int)f2bf(lo) | ((unsigned int)f2bf(hi) << 16);
}
__device__ __forceinline__ u32x4 pack8bf(f32x4 a, f32x4 b) {
  u32x4 r;
  r[0] = pack2bf(a[0], a[1]);
  r[1] = pack2bf(a[2], a[3]);
  r[2] = pack2bf(b[0], b[1]);
  r[3] = pack2bf(b[2], b[3]);
  return r;
}
__device__ __forceinline__ void ld8bf(const unsigned short* p, float* o) {
  short8 v = *(const short8*)p;
#pragma unroll
  for (int q = 0; q < 8; ++q) o[q] = bf2f((unsigned short)v[q]);
}

// ---------- constants ----------
#define LSEQ   4096
#define DMODEL 2048
#define DINNER 4096
#define NHEADS 64
#define PROJ_N 4416    // D_INNER + NHEADS + 2*D_STATE

// ---------- bf16 MFMA GEMM:  C[m][n] = sum_k A[m][k] * B[n][k] ----------
template <bool A_F32, bool OUT_BF16>
__global__ __launch_bounds__(256) void gemm_nt(
    const void* __restrict__ Ap,
    const float* __restrict__ B,
    void* __restrict__ Cp, int K, int ldc, int nmax) {
  __shared__ __attribute__((aligned(16))) unsigned short Asm[128 * 32];
  __shared__ __attribute__((aligned(16))) unsigned short Bsm[128 * 32];
  const int tid = threadIdx.x;
  const int m0 = blockIdx.y * 128;
  const int n0 = blockIdx.x * 128;
  const int wave = tid >> 6, lane = tid & 63;
  const int wm = (wave >> 1) * 64, wn = (wave & 1) * 64;
  const int quad = lane >> 4, l16 = lane & 15;
  const int rowL = tid >> 2;
  const int kk = (tid & 3) * 8;
  const long lK = K;

  int rb0 = n0 + rowL;      if (rb0 > nmax - 1) rb0 = nmax - 1;
  int rb1 = n0 + rowL + 64; if (rb1 > nmax - 1) rb1 = nmax - 1;

  f32x4 zero = {0.f, 0.f, 0.f, 0.f};
  f32x4 acc[4][4];
#pragma unroll
  for (int i = 0; i < 4; ++i)
#pragma unroll
    for (int j = 0; j < 4; ++j) acc[i][j] = zero;

  for (int kt = 0; kt < K; kt += 32) {
    const float* pb0 = B + (long)rb0 * lK + kt + kk;
    const float* pb1 = B + (long)rb1 * lK + kt + kk;
    f32x4 b00 = *(const f32x4*)pb0;
    f32x4 b01 = *(const f32x4*)(pb0 + 4);
    f32x4 b10 = *(const f32x4*)pb1;
    f32x4 b11 = *(const f32x4*)(pb1 + 4);
    u32x4 bw0 = pack8bf(b00, b01);
    u32x4 bw1 = pack8bf(b10, b11);
    u32x4 aw0, aw1;
    if (A_F32) {
      const float* pa = (const float*)Ap + (long)(m0 + rowL) * lK + kt + kk;
      f32x4 a00 = *(const f32x4*)pa;
      f32x4 a01 = *(const f32x4*)(pa + 4);
      f32x4 a10 = *(const f32x4*)(pa + 64 * lK);
      f32x4 a11 = *(const f32x4*)(pa + 64 * lK + 4);
      aw0 = pack8bf(a00, a01);
      aw1 = pack8bf(a10, a11);
    } else {
      const unsigned short* pa = (const unsigned short*)Ap + (long)(m0 + rowL) * lK + kt + kk;
      aw0 = *(const u32x4*)pa;
      aw1 = *(const u32x4*)(pa + 64 * lK);
    }
    *(u32x4*)(Asm + tid * 8) = aw0;
    *(u32x4*)(Asm + tid * 8 + 2048) = aw1;
    *(u32x4*)(Bsm + tid * 8) = bw0;
    *(u32x4*)(Bsm + tid * 8 + 2048) = bw1;
    __syncthreads();
    short8 af[4], bfv[4];
#pragma unroll
    for (int i = 0; i < 4; ++i) {
      af[i]  = *(const short8*)(Asm + (wm + i * 16 + l16) * 32 + quad * 8);
      bfv[i] = *(const short8*)(Bsm + (wn + i * 16 + l16) * 32 + quad * 8);
    }
#pragma unroll
    for (int i = 0; i < 4; ++i)
#pragma unroll
      for (int j = 0; j < 4; ++j)
        acc[i][j] = __builtin_amdgcn_mfma_f32_16x16x32_bf16(af[i], bfv[j], acc[i][j], 0, 0, 0);
    __syncthreads();
  }

#pragma unroll
  for (int i = 0; i < 4; ++i) {
    const int mbase = m0 + wm + i * 16 + quad * 4;
#pragma unroll
    for (int j = 0; j < 4; ++j) {
      const int n = n0 + wn + j * 16 + l16;
      if (n < nmax) {
#pragma unroll
        for (int r = 0; r < 4; ++r) {
          const long o = (long)(mbase + r) * ldc + n;
          if (OUT_BF16) ((unsigned short*)Cp)[o] = f2bf(acc[i][j][r]);
          else          ((float*)Cp)[o] = acc[i][j][r];
        }
      }
    }
  }
}

// ---------- depthwise causal conv (taps=4) + bias + silu, vectorized 8ch/thread ----------
__global__ void conv_silu_kernel(const unsigned short* __restrict__ xin,
                                 const float* __restrict__ cw,
                                 const float* __restrict__ cb,
                                 unsigned short* __restrict__ xout, long nv) {
  long idx = (long)blockIdx.x * blockDim.x + threadIdx.x; // rows*512
  if (idx >= nv) return;
  int c8 = (int)(idx & 511);
  long row = idx >> 9;
  int l = (int)(row & (LSEQ - 1));
  int ch0 = c8 * 8;
  float acc[8];
#pragma unroll
  for (int q = 0; q < 8; ++q) acc[q] = cb[ch0 + q];
#pragma unroll
  for (int t = 0; t < 4; ++t) {
    int ll = l - 3 + t;
    if (ll >= 0) {
      float f[8];
      ld8bf(xin + (row - 3 + t) * 4096 + ch0, f);
#pragma unroll
      for (int q = 0; q < 8; ++q) acc[q] += f[q] * cw[(ch0 + q) * 4 + t];
    }
  }
  short8 o;
#pragma unroll
  for (int q = 0; q < 8; ++q) {
    float a = acc[q] / (1.f + expf(-acc[q]));
    o[q] = (short)f2bf(a);
  }
  *(short8*)(xout + row * 4096 + ch0) = o;
}

// ---------- dt: softplus(dt_in @ dtW^T + dtb) -> fp32 ----------
__global__ void dt_kernel(const unsigned short* __restrict__ proj,
                          const float* __restrict__ dtw,
                          const float* __restrict__ dtb,
                          float* __restrict__ dt, long n) {
  long idx = (long)blockIdx.x * blockDim.x + threadIdx.x; // rows*64
  if (idx >= n) return;
  int h = (int)(idx & 63);
  long row = idx >> 6;
  const unsigned short* p = proj + row * PROJ_N + DINNER;
  float s = dtb[h];
#pragma unroll
  for (int k8 = 0; k8 < 8; ++k8) {
    float f[8];
    ld8bf(p + k8 * 8, f);
    const float* wv = dtw + h * 64 + k8 * 8;
#pragma unroll
    for (int q = 0; q < 8; ++q) s += f[q] * wv[q];
  }
  dt[idx] = (s > 20.f) ? s : log1pf(expf(s));
}

// ==================================================================
// Parallel chunked SSD (3 kernels)
// states layout (TRANSPOSED): states[(gc*64 + h)*8192 + n*64 + p], gc = b*64 + c
// ==================================================================

// ---- phase 1: per-chunk states S_c[p][n] = sum_j dt_j*exp(cs63-cs_j)*X[j][p]*B[j][n]
//      stored transposed: sb[n*64+p]
__global__ __launch_bounds__(256) void ssd_states_kernel(
    const unsigned short* __restrict__ proj,
    const float* __restrict__ dtbuf,
    const float* __restrict__ A_log,
    float* __restrict__ states,
    float* __restrict__ chdec) {
  __shared__ float Bs[64][132];
  __shared__ float Xw[64][68];
  __shared__ float csh[64];
  __shared__ float dth[64];
  const int tid = threadIdx.x;
  const int gc = blockIdx.x;       // b*64 + c
  const int h  = blockIdx.y;
  const long rowbase = (long)gc * 64;

  const float negA = -expf(A_log[h]);
  if (tid < 64) {
    float d = dtbuf[(rowbase + tid) * 64 + h];
    float v = negA * d;
#pragma unroll
    for (int off = 1; off < 64; off <<= 1) {
      float t = __shfl_up(v, off);
      if (tid >= off) v += t;
    }
    csh[tid] = v;
    dth[tid] = d;
  }
  __syncthreads();
  const float cs63 = csh[63];

  for (int idx = tid; idx < 64 * 16; idx += 256) {
    int r = idx >> 4, c8 = idx & 15;
    float f[8];
    ld8bf(proj + (rowbase + r) * PROJ_N + 4160 + c8 * 8, f);
#pragma unroll
    for (int q = 0; q < 8; ++q) Bs[r][c8 * 8 + q] = f[q];
  }
  for (int idx = tid; idx < 64 * 8; idx += 256) {
    int r = idx >> 3, c8 = idx & 7;
    float f[8];
    ld8bf(proj + (rowbase + r) * PROJ_N + h * 64 + c8 * 8, f);
    float w = dth[r] * expf(cs63 - csh[r]);
#pragma unroll
    for (int q = 0; q < 8; ++q) Xw[r][c8 * 8 + q] = w * f[q];
  }
  __syncthreads();

  const int p0 = (tid >> 4) * 4;
  const int n0 = (tid & 15) * 4;
  float a0[4][4] = {};
  float a1[4][4] = {};
  for (int j = 0; j < 64; ++j) {
    f32x4 xv = *(const f32x4*)&Xw[j][p0];
    f32x4 b0 = *(const f32x4*)&Bs[j][n0];
    f32x4 b1 = *(const f32x4*)&Bs[j][n0 + 64];
#pragma unroll
    for (int pp = 0; pp < 4; ++pp)
#pragma unroll
      for (int q = 0; q < 4; ++q) {
        a0[pp][q] += xv[pp] * b0[q];
        a1[pp][q] += xv[pp] * b1[q];
      }
  }
  float* sb = states + ((long)gc * 64 + h) * 8192;
#pragma unroll
  for (int q = 0; q < 4; ++q) {
    f32x4 t0, t1;
#pragma unroll
    for (int pp = 0; pp < 4; ++pp) { t0[pp] = a0[pp][q]; t1[pp] = a1[pp][q]; }
    *(f32x4*)(sb + (n0 + q) * 64 + p0) = t0;
    *(f32x4*)(sb + (n0 + 64 + q) * 64 + p0) = t1;
  }
  if (tid == 0) chdec[gc * 64 + h] = expf(cs63);
}

// ---- phase 2: in-place exclusive prefix scan over chunks (layout-agnostic) ----
__global__ __launch_bounds__(256) void ssd_scan_kernel(
    float* __restrict__ states, const float* __restrict__ chdec) {
  const int by = blockIdx.y;            // b*64 + h
  const int b = by >> 6, h = by & 63;
  const int pn = blockIdx.x * 256 + threadIdx.x;   // 0..8191
  float P = 0.f;
  long base = ((long)b * 64 * 64 + h) * 8192 + pn;
  for (int c = 0; c < 64; ++c) {
    long o = base + (long)c * (64 * 8192);
    float S = states[o];
    states[o] = P;
    P = chdec[(b * 64 + c) * 64 + h] * P + S;
  }
}

// ---- phase 3: Y = Sc @ (dt*X) + exp(cs_i) * (C @ P^T), + D-residual, * silu(z), in place
// block = (gc, head-group of 16), 512 threads, 2 barriers/head, 76.8 KB LDS (2 blk/CU)
__global__ __launch_bounds__(512, 4) void ssd_ydo_gate_kernel(
    const unsigned short* __restrict__ proj,
    const float* __restrict__ dtbuf,
    const float* __restrict__ A_log,
    const float* __restrict__ Dv,
    const float* __restrict__ states,
    unsigned short* __restrict__ zio) {
  __shared__ __attribute__((aligned(16))) char smem[76800];
  float (*Cs)[68]          = (float(*)[68])(smem);             // 17408 B, fp32 C
  float (*Scm)[68]         = (float(*)[68])(smem + 17408);     // 17408 B, scores
  unsigned short (*Xb)[72] = (unsigned short(*)[72])(smem + 34816); // 9216 B, raw X bf16
  float* Pt                = (float*)(smem + 44032);           // 32768 B, state [n][p]
  float (*BsU)[68]         = (float(*)[68])(smem + 44032);     // union: B fp32 (Dm build only)

  const int tid = threadIdx.x;
  const int lane = tid & 63;
  const int gc = blockIdx.x;
  const int hbase = blockIdx.y * 16;
  const long rowbase = (long)gc * 64;

  // ---- stage B, C as fp32 ----
#pragma unroll
  for (int k = 0; k < 2; ++k) {
    int idx = tid + k * 512;
    int r = idx >> 4, c8 = idx & 15;
    const unsigned short* rp = proj + (rowbase + r) * PROJ_N;
    float fB[8], fC[8];
    ld8bf(rp + 4160 + c8 * 8, fB);
    ld8bf(rp + 4288 + c8 * 8, fC);
    f32x4 b0, b1, c0, c1;
#pragma unroll
    for (int q = 0; q < 4; ++q) { b0[q] = fB[q]; b1[q] = fB[q + 4]; c0[q] = fC[q]; c1[q] = fC[q + 4]; }
    *(f32x4*)&BsU[r][c8 * 8] = b0;
    *(f32x4*)&BsU[r][c8 * 8 + 4] = b1;
    *(f32x4*)&Cs[r][c8 * 8] = c0;
    *(f32x4*)&Cs[r][c8 * 8 + 4] = c1;
  }
  __syncthreads();

  // ---- Dm in registers: dm[q] = C[iS] . B[t7 + q*8] ----
  const int iS = tid >> 3, t7 = tid & 7;
  float dm[8] = {};
  for (int n8 = 0; n8 < 16; ++n8) {
    f32x4 cv0 = *(const f32x4*)&Cs[iS][n8 * 8];
    f32x4 cv1 = *(const f32x4*)&Cs[iS][n8 * 8 + 4];
#pragma unroll
    for (int q = 0; q < 8; ++q) {
      int j = t7 + q * 8;
      f32x4 bv0 = *(const f32x4*)&BsU[j][n8 * 8];
      f32x4 bv1 = *(const f32x4*)&BsU[j][n8 * 8 + 4];
      dm[q] += cv0[0] * bv0[0] + cv0[1] * bv0[1] + cv0[2] * bv0[2] + cv0[3] * bv0[3]
             + cv1[0] * bv1[0] + cv1[1] * bv1[1] + cv1[2] * bv1[2] + cv1[3] * bv1[3];
    }
  }
  __syncthreads();   // BsU region now free for Pt

  const int i0 = (tid >> 4) * 2;
  const int p0 = (tid & 15) * 4;

  for (int hh = 0; hh < 16; ++hh) {
    const int h = hbase + hh;
    const float Dh = Dv[h];
    const float negA = -expf(A_log[h]);

    // ---- early global loads ----
    const float* sb2 = states + ((long)gc * 64 + h) * 8192;
    f32x4 s0 = *(const f32x4*)(sb2 + tid * 4);
    f32x4 s1 = *(const f32x4*)(sb2 + 2048 + tid * 4);
    f32x4 s2 = *(const f32x4*)(sb2 + 4096 + tid * 4);
    f32x4 s3 = *(const f32x4*)(sb2 + 6144 + tid * 4);
    short8 x8 = *(const short8*)(proj + (rowbase + iS) * PROJ_N + h * 64 + t7 * 8);
    float d = dtbuf[(rowbase + lane) * 64 + h];

    // ---- register scan: v = cs[lane] (all waves redundantly) ----
    float v = negA * d;
    {
      float t;
      t = __shfl_up(v, 1);  if (lane >= 1)  v += t;
      t = __shfl_up(v, 2);  if (lane >= 2)  v += t;
      t = __shfl_up(v, 4);  if (lane >= 4)  v += t;
      t = __shfl_up(v, 8);  if (lane >= 8)  v += t;
      t = __shfl_up(v, 16); if (lane >= 16) v += t;
      t = __shfl_up(v, 32); if (lane >= 32) v += t;
    }

    // ---- LDS writes: Pt (straight copy), Xb, Scm ----
    *(f32x4*)&Pt[tid * 4]        = s0;
    *(f32x4*)&Pt[2048 + tid * 4] = s1;
    *(f32x4*)&Pt[4096 + tid * 4] = s2;
    *(f32x4*)&Pt[6144 + tid * 4] = s3;
    *(short8*)&Xb[iS][t7 * 8] = x8;
    {
      const float ci = __shfl(v, iS);
#pragma unroll
      for (int q = 0; q < 8; ++q) {
        int j = t7 + q * 8;
        float cj = __shfl(v, j);
        float dj = __shfl(d, j);
        Scm[iS][j] = (j <= iS) ? dm[q] * expf(ci - cj) * dj : 0.f;
      }
    }
    __syncthreads();   // A: Pt, Xb, Scm ready

    // ---- early gate loads ----
    const long r0w = rowbase + i0, r1w = r0w + 1;
    const long zo0 = r0w * 4096 + h * 64 + p0;
    const long zo1 = r1w * 4096 + h * 64 + p0;
    s16x4 zv0 = *(const s16x4*)&zio[zo0];
    s16x4 zv1 = *(const s16x4*)&zio[zo1];
    s16x4 xv0 = *(const s16x4*)(proj + r0w * PROJ_N + h * 64 + p0);
    s16x4 xv1 = *(const s16x4*)(proj + r1w * PROJ_N + h * 64 + p0);

    // ---- Y_diag: ya[i][p] = sum_j Scm[i][j] * X[j][p] ----
    float ya0[4] = {}, ya1[4] = {};
#pragma unroll 4
    for (int j = 0; j < 64; ++j) {
      float sc0 = Scm[i0][j], sc1 = Scm[i0 + 1][j];
      s16x4 xj = *(const s16x4*)&Xb[j][p0];
#pragma unroll
      for (int k = 0; k < 4; ++k) {
        float xv = bf2f((unsigned short)xj[k]);
        ya0[k] += sc0 * xv;
        ya1[k] += sc1 * xv;
      }
    }
    // ---- Y_off: yb[i][p] = sum_n C[i][n] * Pt[n][p] ----
    float yb0[4] = {}, yb1[4] = {};
#pragma unroll 2
    for (int n8 = 0; n8 < 16; ++n8) {
      f32x4 ca0 = *(const f32x4*)&Cs[i0][n8 * 8];
      f32x4 ca1 = *(const f32x4*)&Cs[i0][n8 * 8 + 4];
      f32x4 cb0 = *(const f32x4*)&Cs[i0 + 1][n8 * 8];
      f32x4 cb1 = *(const f32x4*)&Cs[i0 + 1][n8 * 8 + 4];
#pragma unroll
      for (int q = 0; q < 8; ++q) {
        f32x4 pv = *(const f32x4*)&Pt[(n8 * 8 + q) * 64 + p0];
        float c0 = (q < 4) ? ca0[q] : ca1[q - 4];
        float c1 = (q < 4) ? cb0[q] : cb1[q - 4];
#pragma unroll
        for (int k = 0; k < 4; ++k) {
          yb0[k] += c0 * pv[k];
          yb1[k] += c1 * pv[k];
        }
      }
    }
    // ---- gate + store ----
    const float e0 = expf(__shfl(v, i0));
    const float e1 = expf(__shfl(v, i0 + 1));
    s16x4 o0, o1;
#pragma unroll
    for (int k = 0; k < 4; ++k) {
      float y = ya0[k] + e0 * yb0[k];
      float xraw = bf2f((unsigned short)xv0[k]);
      float zz = bf2f((unsigned short)zv0[k]);
      float sz = zz / (1.f + expf(-zz));
      o0[k] = (short)f2bf((y + xraw * Dh) * sz);
      y = ya1[k] + e1 * yb1[k];
      xraw = bf2f((unsigned short)xv1[k]);
      zz = bf2f((unsigned short)zv1[k]);
      sz = zz / (1.f + expf(-zz));
      o1[k] = (short)f2bf((y + xraw * Dh) * sz);
    }
    *(s16x4*)&zio[zo0] = o0;
    *(s16x4*)&zio[zo1] = o1;
    __syncthreads();   // B: LDS consumed, next head may overwrite
  }
}

// ---------- OLD serial SSD (fallback when workspace too small) ----------
__global__ __launch_bounds__(512) void ssd_gate_kernel(
    const unsigned short* __restrict__ proj,
    const float* __restrict__ dtbuf,
    const float* __restrict__ A_log,
    const float* __restrict__ Dv,
    unsigned short* __restrict__ zio) {
  __shared__ float st[64][128];
  __shared__ float Bs[64][128];
  __shared__ float Cs[64][128];
  __shared__ float Xs[64][64];
  __shared__ float Sc[64][64];
  __shared__ float cs[64];
  __shared__ float dtc[64];

  const int tid = threadIdx.x;
  const int bl = blockIdx.x >> 6;
  const int h = blockIdx.x & 63;
  const float negA = -expf(A_log[h]);
  const float Dh = Dv[h];

  for (int i = tid; i < 64 * 128; i += 512) (&st[0][0])[i] = 0.f;

  for (int c = 0; c < 64; ++c) {
    const long rowbase = (long)bl * LSEQ + c * 64;
    if (tid < 64) dtc[tid] = dtbuf[(rowbase + tid) * 64 + h];
    __syncthreads();
    if (tid == 0) {
      float run = 0.f;
      for (int j = 0; j < 64; ++j) { run += negA * dtc[j]; cs[j] = run; }
    }
    {
      const int j = tid >> 3;
      const int c8 = tid & 7;
      const unsigned short* rp = proj + (rowbase + j) * PROJ_N;
      const float dj = dtc[j];
#pragma unroll
      for (int q = 0; q < 8; ++q)
        Xs[j][c8 * 8 + q] = bf2f(rp[h * 64 + c8 * 8 + q]) * dj;
#pragma unroll
      for (int q = 0; q < 16; ++q) {
        Bs[j][c8 * 16 + q] = bf2f(rp[4160 + c8 * 16 + q]);
        Cs[j][c8 * 16 + q] = bf2f(rp[4288 + c8 * 16 + q]);
      }
    }
    __syncthreads();
    {
      const int i0 = (tid >> 4) * 2;
      const int j0 = (tid & 15) * 4;
      float a[2][4] = {};
      for (int n = 0; n < 128; ++n) {
        float c0 = Cs[i0][n], c1 = Cs[i0 + 1][n];
        float b0 = Bs[j0][n], b1 = Bs[j0 + 1][n], b2 = Bs[j0 + 2][n], b3 = Bs[j0 + 3][n];
        a[0][0] += c0 * b0; a[0][1] += c0 * b1; a[0][2] += c0 * b2; a[0][3] += c0 * b3;
        a[1][0] += c1 * b0; a[1][1] += c1 * b1; a[1][2] += c1 * b2; a[1][3] += c1 * b3;
      }
#pragma unroll
      for (int ii = 0; ii < 2; ++ii)
#pragma unroll
        for (int jj = 0; jj < 4; ++jj) {
          int i = i0 + ii, j = j0 + jj;
          Sc[i][j] = (j <= i) ? a[ii][jj] * expf(cs[i] - cs[j]) : 0.f;
        }
    }
    __syncthreads();
    {
      const int i0 = (tid >> 4) * 2;
      const int p0 = (tid & 15) * 4;
      float a1[2][4] = {};
      for (int j = 0; j < 64; ++j) {
        float s0 = Sc[i0][j], s1 = Sc[i0 + 1][j];
        float x0 = Xs[j][p0], x1 = Xs[j][p0 + 1], x2 = Xs[j][p0 + 2], x3 = Xs[j][p0 + 3];
        a1[0][0] += s0 * x0; a1[0][1] += s0 * x1; a1[0][2] += s0 * x2; a1[0][3] += s0 * x3;
        a1[1][0] += s1 * x0; a1[1][1] += s1 * x1; a1[1][2] += s1 * x2; a1[1][3] += s1 * x3;
      }
      float a2[2][4] = {};
      for (int n = 0; n < 128; ++n) {
        float c0 = Cs[i0][n], c1 = Cs[i0 + 1][n];
        float t0 = st[p0][n], t1 = st[p0 + 1][n], t2 = st[p0 + 2][n], t3 = st[p0 + 3][n];
        a2[0][0] += c0 * t0; a2[0][1] += c0 * t1; a2[0][2] += c0 * t2; a2[0][3] += c0 * t3;
        a2[1][0] += c1 * t0; a2[1][1] += c1 * t1; a2[1][2] += c1 * t2; a2[1][3] += c1 * t3;
      }
      float e0 = expf(cs[i0]), e1 = expf(cs[i0 + 1]);
#pragma unroll
      for (int ii = 0; ii < 2; ++ii) {
        const long r = rowbase + i0 + ii;
        const long zo = r * 4096 + h * 64 + p0;
        const unsigned short* xr = proj + r * PROJ_N + h * 64 + p0;
        float e = ii ? e1 : e0;
#pragma unroll
        for (int pp = 0; pp < 4; ++pp) {
          float y = a1[ii][pp] + e * a2[ii][pp];
          float xraw = bf2f(xr[pp]);
          float zz = bf2f(zio[zo + pp]);
          float sz = zz / (1.f + expf(-zz));
          zio[zo + pp] = f2bf((y + xraw * Dh) * sz);
        }
      }
    }
    __syncthreads();
    {
      const int j = tid >> 3;
      const int p0 = (tid & 7) * 8;
      float f = expf(cs[63] - cs[j]);
#pragma unroll
      for (int q = 0; q < 8; ++q) Xs[j][p0 + q] *= f;
    }
    __syncthreads();
    {
      const float dec = expf(cs[63]);
      const int p0 = (tid >> 5) * 4;
      const int n0 = (tid & 31) * 4;
      float a[4][4] = {};
      for (int j = 0; j < 64; ++j) {
        float x0 = Xs[j][p0], x1 = Xs[j][p0 + 1], x2 = Xs[j][p0 + 2], x3 = Xs[j][p0 + 3];
        float b0 = Bs[j][n0], b1 = Bs[j][n0 + 1], b2 = Bs[j][n0 + 2], b3 = Bs[j][n0 + 3];
        a[0][0] += x0 * b0; a[0][1] += x0 * b1; a[0][2] += x0 * b2; a[0][3] += x0 * b3;
        a[1][0] += x1 * b0; a[1][1] += x1 * b1; a[1][2] += x1 * b2; a[1][3] += x1 * b3;
        a[2][0] += x2 * b0; a[2][1] += x2 * b1; a[2][2] += x2 * b2; a[2][3] += x2 * b3;
        a[3][0] += x3 * b0; a[3][1] += x3 * b1; a[3][2] += x3 * b2; a[3][3] += x3 * b3;
      }
#pragma unroll
      for (int pp = 0; pp < 4; ++pp)
#pragma unroll
        for (int nn = 0; nn < 4; ++nn)
          st[p0 + pp][n0 + nn] = dec * st[p0 + pp][n0 + nn] + a[pp][nn];
    }
    __syncthreads();
  }
}

// ---------- launch ----------
extern "C" void kernel_launch(void* const* d_in, const int* in_sizes, int n_in,
                              void* d_out, int out_size, void* d_ws, size_t ws_size,
                              hipStream_t stream) {
  (void)in_sizes; (void)n_in; (void)out_size;
  const float* x    = (const float*)d_in[0];
  const float* w1   = (const float*)d_in[1]; // 8192 x 2048
  const float* cw   = (const float*)d_in[2]; // 4096 x 4
  const float* cb   = (const float*)d_in[3]; // 4096
  const float* w2   = (const float*)d_in[4]; // 4416 x 4096
  const float* dtw  = (const float*)d_in[5]; // 64 x 64
  const float* dtb  = (const float*)d_in[6]; // 64
  const float* Alog = (const float*)d_in[7]; // 64
  const float* Dv   = (const float*)d_in[8]; // 64
  const float* w3   = (const float*)d_in[9]; // 2048 x 4096
  float* out = (float*)d_out;

  const size_t NEED8 = 410025984ull;   // CR=8192 new path
  const size_t NEED4 = 205012992ull;   // CR=4096 new path
  int CR; bool newpath;
  if      (ws_size >= NEED8)               { CR = 8192; newpath = true;  }
  else if (ws_size >= NEED4)               { CR = 4096; newpath = true;  }
  else if (ws_size >= (size_t)8192 * 17280){ CR = 8192; newpath = false; }
  else if (ws_size >= (size_t)4096 * 17280){ CR = 4096; newpath = false; }
  else return;  // diagnostic: error == 8.69e-2 means ws too small

  char* w = (char*)d_ws;
  const size_t S1 = (size_t)CR * 4096 * 2;
  const size_t S2 = (size_t)CR * PROJ_N * 2;
  const int nb = CR / LSEQ;
  unsigned short* xc   = (unsigned short*)(w);       // conv out   [0, S1)
  unsigned short* xp   = (unsigned short*)(w + S1);  // pre-conv   (inside proj region)
  unsigned short* proj = (unsigned short*)(w + S1);  // x_proj out — over xp (dead)
  unsigned short* z    = (unsigned short*)(w);       // z branch — over xc (dead)
  float* dtf           = (float*)(w + S1 + S2);
  float* chdec         = (float*)(w + S1 + S2 + (size_t)CR * 256);
  float* states        = (float*)(w + S1 + S2 + (size_t)CR * 256 + (size_t)nb * 16384);

  for (int r0 = 0; r0 < 8192; r0 += CR) {
    const float* xr = x + (size_t)r0 * DMODEL;
    // 1) in_proj x-half -> xp (A fp32, out bf16)
    dim3 g1(DINNER / 128, CR / 128);
    gemm_nt<true, true><<<g1, 256, 0, stream>>>(xr, w1, xp, DMODEL, DINNER, DINNER);
    // 2) conv + silu -> xc (vectorized: 8 ch / thread)
    conv_silu_kernel<<<((long)CR * 512) / 256, 256, 0, stream>>>(xp, cw, cb, xc, (long)CR * 512);
    // 3) x_proj -> proj (A bf16, out bf16; overwrites xp region)
    dim3 g2((PROJ_N + 127) / 128, CR / 128);
    gemm_nt<false, true><<<g2, 256, 0, stream>>>(xc, w2, proj, DINNER, PROJ_N, PROJ_N);
    // 4) dt
    dt_kernel<<<((long)CR * NHEADS) / 256, 256, 0, stream>>>(proj, dtw, dtb, dtf, (long)CR * NHEADS);
    // 5) in_proj z-half -> z (A fp32, out bf16; overwrites xc region)
    gemm_nt<true, true><<<g1, 256, 0, stream>>>(xr, w1 + (size_t)DINNER * DMODEL, z, DMODEL, DINNER, DINNER);
    // 6) SSD + gate, in place over z
    if (newpath) {
      ssd_states_kernel<<<dim3(nb * 64, 64), 256, 0, stream>>>(proj, dtf, Alog, states, chdec);
      ssd_scan_kernel<<<dim3(32, nb * 64), 256, 0, stream>>>(states, chdec);
      ssd_ydo_gate_kernel<<<dim3(nb * 64, 4), 512, 0, stream>>>(proj, dtf, Alog, Dv, states, z);
    } else {
      ssd_gate_kernel<<<(CR / LSEQ) * NHEADS, 512, 0, stream>>>(proj, dtf, Alog, Dv, z);
    }
    // 7) out_proj -> d_out (A bf16, out fp32)
    dim3 g3(DMODEL / 128, CR / 128);
    gemm_nt<false, false><<<g3, 256, 0, stream>>>(z, w3, out + (size_t)r0 * DMODEL, DINNER, DMODEL, DMODEL);
  }
}

// Round 4
// 2155.730 us; speedup vs baseline: 3.6065x; 1.2296x over previous
//
#include <hip/hip_runtime.h>

// ---------- types / helpers ----------
typedef __attribute__((ext_vector_type(8))) short short8;
typedef __attribute__((ext_vector_type(4))) short s16x4;
typedef __attribute__((ext_vector_type(4))) float f32x4;
typedef __attribute__((ext_vector_type(4))) unsigned int u32x4;

typedef __attribute__((address_space(3))) unsigned int lds_u32;
typedef __attribute__((address_space(1))) unsigned int glob_u32;

__device__ __forceinline__ float bf2f(unsigned short s) {
  unsigned int v = ((unsigned int)s) << 16; float f; __builtin_memcpy(&f, &v, 4); return f;
}
__device__ __forceinline__ unsigned short f2bf(float f) {
  unsigned int u; __builtin_memcpy(&u, &f, 4);
  u += 0x7fffu + ((u >> 16) & 1u);   // RNE (finite values only here)
  return (unsigned short)(u >> 16);
}
__device__ __forceinline__ unsigned int pack2bf(float lo, float hi) {
  return (unsigned int)f2bf(lo) | ((unsigned int)f2bf(hi) << 16);
}
__device__ __forceinline__ u32x4 pack8bf(f32x4 a, f32x4 b) {
  u32x4 r;
  r[0] = pack2bf(a[0], a[1]);
  r[1] = pack2bf(a[2], a[3]);
  r[2] = pack2bf(b[0], b[1]);
  r[3] = pack2bf(b[2], b[3]);
  return r;
}
__device__ __forceinline__ void ld8bf(const unsigned short* p, float* o) {
  short8 v = *(const short8*)p;
#pragma unroll
  for (int q = 0; q < 8; ++q) o[q] = bf2f((unsigned short)v[q]);
}
// async global->LDS, 16B per lane. LDS dest: wave-uniform base + lane*16.
__device__ __forceinline__ void gl2lds16(const unsigned short* g, unsigned short* l) {
  __builtin_amdgcn_global_load_lds((const glob_u32*)g, (lds_u32*)l, 16, 0, 0);
}

// ---------- constants ----------
#define LSEQ   4096
#define DMODEL 2048
#define DINNER 4096
#define NHEADS 64
#define PROJ_N 4416    // D_INNER + NHEADS + 2*D_STATE

// ---------- fp32 -> bf16 bulk convert (RNE, identical to pack8bf path) ----------
__global__ void f2bf_kernel(const float* __restrict__ in, unsigned short* __restrict__ out, long n8) {
  long i = (long)blockIdx.x * blockDim.x + threadIdx.x;
  if (i >= n8) return;
  f32x4 a = *(const f32x4*)(in + i * 8);
  f32x4 b = *(const f32x4*)(in + i * 8 + 4);
  *(u32x4*)(out + i * 8) = pack8bf(a, b);
}

// ---------- all-bf16 MFMA GEMM (m97 structure): C[m][n] = sum_k A[m][k]*B[n][k] ----
// 128x128 tile, BK=32, global_load_lds width-16 staging, XCD-chunked swizzle.
template <bool OUT_BF16>
__global__ __launch_bounds__(256) void gemm_bb(
    const unsigned short* __restrict__ A,   // M x K bf16 row-major
    const unsigned short* __restrict__ B,   // nmax x K bf16 row-major (rows clamped)
    void* __restrict__ Cp, int K, int ldc, int nmax) {
  __shared__ __attribute__((aligned(16))) unsigned short Asm[128 * 32];
  __shared__ __attribute__((aligned(16))) unsigned short Bsm[128 * 32];
  const int tid = threadIdx.x;
  // XCD-aware chunked swizzle (bijective when nwg % 8 == 0; all our grids are)
  const int nbx = gridDim.x;
  int flat = blockIdx.y * nbx + blockIdx.x;
  const int nwg = nbx * gridDim.y;
  if ((nwg & 7) == 0) { const int cpx = nwg >> 3; flat = (flat & 7) * cpx + (flat >> 3); }
  const int m0 = (flat / nbx) * 128;
  const int n0 = (flat % nbx) * 128;

  const int wave = tid >> 6, lane = tid & 63;
  const int wm = (wave >> 1) * 64, wn = (wave & 1) * 64;
  const int quad = lane >> 4, l16 = lane & 15;
  const int rowL = tid >> 2;
  const int kk = (tid & 3) * 8;
  const long lK = K;

  int rb0 = n0 + rowL;      if (rb0 > nmax - 1) rb0 = nmax - 1;
  int rb1 = n0 + rowL + 64; if (rb1 > nmax - 1) rb1 = nmax - 1;
  const unsigned short* pa0 = A + (long)(m0 + rowL) * lK + kk;
  const unsigned short* pa1 = pa0 + 64 * lK;
  const unsigned short* pb0 = B + (long)rb0 * lK + kk;
  const unsigned short* pb1 = B + (long)rb1 * lK + kk;

  f32x4 zero = {0.f, 0.f, 0.f, 0.f};
  f32x4 acc[4][4];
#pragma unroll
  for (int i = 0; i < 4; ++i)
#pragma unroll
    for (int j = 0; j < 4; ++j) acc[i][j] = zero;

  for (int kt = 0; kt < K; kt += 32) {
    gl2lds16(pa0 + kt, Asm + tid * 8);
    gl2lds16(pa1 + kt, Asm + tid * 8 + 2048);
    gl2lds16(pb0 + kt, Bsm + tid * 8);
    gl2lds16(pb1 + kt, Bsm + tid * 8 + 2048);
    __syncthreads();
    short8 af[4], bfv[4];
#pragma unroll
    for (int i = 0; i < 4; ++i) {
      af[i]  = *(const short8*)(Asm + (wm + i * 16 + l16) * 32 + quad * 8);
      bfv[i] = *(const short8*)(Bsm + (wn + i * 16 + l16) * 32 + quad * 8);
    }
#pragma unroll
    for (int i = 0; i < 4; ++i)
#pragma unroll
      for (int j = 0; j < 4; ++j)
        acc[i][j] = __builtin_amdgcn_mfma_f32_16x16x32_bf16(af[i], bfv[j], acc[i][j], 0, 0, 0);
    __syncthreads();
  }

#pragma unroll
  for (int i = 0; i < 4; ++i) {
    const int mbase = m0 + wm + i * 16 + quad * 4;
#pragma unroll
    for (int j = 0; j < 4; ++j) {
      const int n = n0 + wn + j * 16 + l16;
      if (n < nmax) {
#pragma unroll
        for (int r = 0; r < 4; ++r) {
          const long o = (long)(mbase + r) * ldc + n;
          if (OUT_BF16) ((unsigned short*)Cp)[o] = f2bf(acc[i][j][r]);
          else          ((float*)Cp)[o] = acc[i][j][r];
        }
      }
    }
  }
}

// ---------- legacy mixed GEMM (fallback path only) ----------
template <bool A_F32, bool OUT_BF16>
__global__ __launch_bounds__(256) void gemm_nt(
    const void* __restrict__ Ap,
    const float* __restrict__ B,
    void* __restrict__ Cp, int K, int ldc, int nmax) {
  __shared__ __attribute__((aligned(16))) unsigned short Asm[128 * 32];
  __shared__ __attribute__((aligned(16))) unsigned short Bsm[128 * 32];
  const int tid = threadIdx.x;
  const int m0 = blockIdx.y * 128;
  const int n0 = blockIdx.x * 128;
  const int wave = tid >> 6, lane = tid & 63;
  const int wm = (wave >> 1) * 64, wn = (wave & 1) * 64;
  const int quad = lane >> 4, l16 = lane & 15;
  const int rowL = tid >> 2;
  const int kk = (tid & 3) * 8;
  const long lK = K;

  int rb0 = n0 + rowL;      if (rb0 > nmax - 1) rb0 = nmax - 1;
  int rb1 = n0 + rowL + 64; if (rb1 > nmax - 1) rb1 = nmax - 1;

  f32x4 zero = {0.f, 0.f, 0.f, 0.f};
  f32x4 acc[4][4];
#pragma unroll
  for (int i = 0; i < 4; ++i)
#pragma unroll
    for (int j = 0; j < 4; ++j) acc[i][j] = zero;

  for (int kt = 0; kt < K; kt += 32) {
    const float* pb0 = B + (long)rb0 * lK + kt + kk;
    const float* pb1 = B + (long)rb1 * lK + kt + kk;
    f32x4 b00 = *(const f32x4*)pb0;
    f32x4 b01 = *(const f32x4*)(pb0 + 4);
    f32x4 b10 = *(const f32x4*)pb1;
    f32x4 b11 = *(const f32x4*)(pb1 + 4);
    u32x4 bw0 = pack8bf(b00, b01);
    u32x4 bw1 = pack8bf(b10, b11);
    u32x4 aw0, aw1;
    if (A_F32) {
      const float* pa = (const float*)Ap + (long)(m0 + rowL) * lK + kt + kk;
      f32x4 a00 = *(const f32x4*)pa;
      f32x4 a01 = *(const f32x4*)(pa + 4);
      f32x4 a10 = *(const f32x4*)(pa + 64 * lK);
      f32x4 a11 = *(const f32x4*)(pa + 64 * lK + 4);
      aw0 = pack8bf(a00, a01);
      aw1 = pack8bf(a10, a11);
    } else {
      const unsigned short* pa = (const unsigned short*)Ap + (long)(m0 + rowL) * lK + kt + kk;
      aw0 = *(const u32x4*)pa;
      aw1 = *(const u32x4*)(pa + 64 * lK);
    }
    *(u32x4*)(Asm + tid * 8) = aw0;
    *(u32x4*)(Asm + tid * 8 + 2048) = aw1;
    *(u32x4*)(Bsm + tid * 8) = bw0;
    *(u32x4*)(Bsm + tid * 8 + 2048) = bw1;
    __syncthreads();
    short8 af[4], bfv[4];
#pragma unroll
    for (int i = 0; i < 4; ++i) {
      af[i]  = *(const short8*)(Asm + (wm + i * 16 + l16) * 32 + quad * 8);
      bfv[i] = *(const short8*)(Bsm + (wn + i * 16 + l16) * 32 + quad * 8);
    }
#pragma unroll
    for (int i = 0; i < 4; ++i)
#pragma unroll
      for (int j = 0; j < 4; ++j)
        acc[i][j] = __builtin_amdgcn_mfma_f32_16x16x32_bf16(af[i], bfv[j], acc[i][j], 0, 0, 0);
    __syncthreads();
  }

#pragma unroll
  for (int i = 0; i < 4; ++i) {
    const int mbase = m0 + wm + i * 16 + quad * 4;
#pragma unroll
    for (int j = 0; j < 4; ++j) {
      const int n = n0 + wn + j * 16 + l16;
      if (n < nmax) {
#pragma unroll
        for (int r = 0; r < 4; ++r) {
          const long o = (long)(mbase + r) * ldc + n;
          if (OUT_BF16) ((unsigned short*)Cp)[o] = f2bf(acc[i][j][r]);
          else          ((float*)Cp)[o] = acc[i][j][r];
        }
      }
    }
  }
}

// ---------- depthwise causal conv (taps=4) + bias + silu, vectorized 8ch/thread ----------
__global__ void conv_silu_kernel(const unsigned short* __restrict__ xin,
                                 const float* __restrict__ cw,
                                 const float* __restrict__ cb,
                                 unsigned short* __restrict__ xout, long nv) {
  long idx = (long)blockIdx.x * blockDim.x + threadIdx.x; // rows*512
  if (idx >= nv) return;
  int c8 = (int)(idx & 511);
  long row = idx >> 9;
  int l = (int)(row & (LSEQ - 1));
  int ch0 = c8 * 8;
  float acc[8];
#pragma unroll
  for (int q = 0; q < 8; ++q) acc[q] = cb[ch0 + q];
#pragma unroll
  for (int t = 0; t < 4; ++t) {
    int ll = l - 3 + t;
    if (ll >= 0) {
      float f[8];
      ld8bf(xin + (row - 3 + t) * 4096 + ch0, f);
#pragma unroll
      for (int q = 0; q < 8; ++q) acc[q] += f[q] * cw[(ch0 + q) * 4 + t];
    }
  }
  short8 o;
#pragma unroll
  for (int q = 0; q < 8; ++q) {
    float a = acc[q] / (1.f + expf(-acc[q]));
    o[q] = (short)f2bf(a);
  }
  *(short8*)(xout + row * 4096 + ch0) = o;
}

// ---------- dt: softplus(dt_in @ dtW^T + dtb) -> fp32 ----------
__global__ void dt_kernel(const unsigned short* __restrict__ proj,
                          const float* __restrict__ dtw,
                          const float* __restrict__ dtb,
                          float* __restrict__ dt, long n) {
  long idx = (long)blockIdx.x * blockDim.x + threadIdx.x; // rows*64
  if (idx >= n) return;
  int h = (int)(idx & 63);
  long row = idx >> 6;
  const unsigned short* p = proj + row * PROJ_N + DINNER;
  float s = dtb[h];
#pragma unroll
  for (int k8 = 0; k8 < 8; ++k8) {
    float f[8];
    ld8bf(p + k8 * 8, f);
    const float* wv = dtw + h * 64 + k8 * 8;
#pragma unroll
    for (int q = 0; q < 8; ++q) s += f[q] * wv[q];
  }
  dt[idx] = (s > 20.f) ? s : log1pf(expf(s));
}

// ==================================================================
// Parallel chunked SSD (3 kernels)
// states layout (TRANSPOSED): states[(gc*64 + h)*8192 + n*64 + p], gc = b*64 + c
// ==================================================================

__global__ __launch_bounds__(256) void ssd_states_kernel(
    const unsigned short* __restrict__ proj,
    const float* __restrict__ dtbuf,
    const float* __restrict__ A_log,
    float* __restrict__ states,
    float* __restrict__ chdec) {
  __shared__ float Bs[64][132];
  __shared__ float Xw[64][68];
  __shared__ float csh[64];
  __shared__ float dth[64];
  const int tid = threadIdx.x;
  const int gc = blockIdx.x;       // b*64 + c
  const int h  = blockIdx.y;
  const long rowbase = (long)gc * 64;

  const float negA = -expf(A_log[h]);
  if (tid < 64) {
    float d = dtbuf[(rowbase + tid) * 64 + h];
    float v = negA * d;
#pragma unroll
    for (int off = 1; off < 64; off <<= 1) {
      float t = __shfl_up(v, off);
      if (tid >= off) v += t;
    }
    csh[tid] = v;
    dth[tid] = d;
  }
  __syncthreads();
  const float cs63 = csh[63];

  for (int idx = tid; idx < 64 * 16; idx += 256) {
    int r = idx >> 4, c8 = idx & 15;
    float f[8];
    ld8bf(proj + (rowbase + r) * PROJ_N + 4160 + c8 * 8, f);
#pragma unroll
    for (int q = 0; q < 8; ++q) Bs[r][c8 * 8 + q] = f[q];
  }
  for (int idx = tid; idx < 64 * 8; idx += 256) {
    int r = idx >> 3, c8 = idx & 7;
    float f[8];
    ld8bf(proj + (rowbase + r) * PROJ_N + h * 64 + c8 * 8, f);
    float w = dth[r] * expf(cs63 - csh[r]);
#pragma unroll
    for (int q = 0; q < 8; ++q) Xw[r][c8 * 8 + q] = w * f[q];
  }
  __syncthreads();

  const int p0 = (tid >> 4) * 4;
  const int n0 = (tid & 15) * 4;
  float a0[4][4] = {};
  float a1[4][4] = {};
  for (int j = 0; j < 64; ++j) {
    f32x4 xv = *(const f32x4*)&Xw[j][p0];
    f32x4 b0 = *(const f32x4*)&Bs[j][n0];
    f32x4 b1 = *(const f32x4*)&Bs[j][n0 + 64];
#pragma unroll
    for (int pp = 0; pp < 4; ++pp)
#pragma unroll
      for (int q = 0; q < 4; ++q) {
        a0[pp][q] += xv[pp] * b0[q];
        a1[pp][q] += xv[pp] * b1[q];
      }
  }
  float* sb = states + ((long)gc * 64 + h) * 8192;
#pragma unroll
  for (int q = 0; q < 4; ++q) {
    f32x4 t0, t1;
#pragma unroll
    for (int pp = 0; pp < 4; ++pp) { t0[pp] = a0[pp][q]; t1[pp] = a1[pp][q]; }
    *(f32x4*)(sb + (n0 + q) * 64 + p0) = t0;
    *(f32x4*)(sb + (n0 + 64 + q) * 64 + p0) = t1;
  }
  if (tid == 0) chdec[gc * 64 + h] = expf(cs63);
}

__global__ __launch_bounds__(256) void ssd_scan_kernel(
    float* __restrict__ states, const float* __restrict__ chdec) {
  const int by = blockIdx.y;            // b*64 + h
  const int b = by >> 6, h = by & 63;
  const int pn = blockIdx.x * 256 + threadIdx.x;   // 0..8191
  float P = 0.f;
  long base = ((long)b * 64 * 64 + h) * 8192 + pn;
  for (int c = 0; c < 64; ++c) {
    long o = base + (long)c * (64 * 8192);
    float S = states[o];
    states[o] = P;
    P = chdec[(b * 64 + c) * 64 + h] * P + S;
  }
}

// ---- phase 3: Y = Sc @ (dt*X) + exp(cs_i) * (C @ P^T), + D-residual, * silu(z), in place
__global__ __launch_bounds__(512, 4) void ssd_ydo_gate_kernel(
    const unsigned short* __restrict__ proj,
    const float* __restrict__ dtbuf,
    const float* __restrict__ A_log,
    const float* __restrict__ Dv,
    const float* __restrict__ states,
    unsigned short* __restrict__ zio) {
  __shared__ __attribute__((aligned(16))) char smem[76800];
  float (*Cs)[68]          = (float(*)[68])(smem);             // 17408 B, fp32 C
  float (*Scm)[68]         = (float(*)[68])(smem + 17408);     // 17408 B, scores
  unsigned short (*Xb)[72] = (unsigned short(*)[72])(smem + 34816); // 9216 B, raw X bf16
  float* Pt                = (float*)(smem + 44032);           // 32768 B, state [n][p]
  float (*BsU)[68]         = (float(*)[68])(smem + 44032);     // union: B fp32 (Dm build only)

  const int tid = threadIdx.x;
  const int lane = tid & 63;
  const int gc = blockIdx.x;
  const int hbase = blockIdx.y * 16;
  const long rowbase = (long)gc * 64;

#pragma unroll
  for (int k = 0; k < 2; ++k) {
    int idx = tid + k * 512;
    int r = idx >> 4, c8 = idx & 15;
    const unsigned short* rp = proj + (rowbase + r) * PROJ_N;
    float fB[8], fC[8];
    ld8bf(rp + 4160 + c8 * 8, fB);
    ld8bf(rp + 4288 + c8 * 8, fC);
    f32x4 b0, b1, c0, c1;
#pragma unroll
    for (int q = 0; q < 4; ++q) { b0[q] = fB[q]; b1[q] = fB[q + 4]; c0[q] = fC[q]; c1[q] = fC[q + 4]; }
    *(f32x4*)&BsU[r][c8 * 8] = b0;
    *(f32x4*)&BsU[r][c8 * 8 + 4] = b1;
    *(f32x4*)&Cs[r][c8 * 8] = c0;
    *(f32x4*)&Cs[r][c8 * 8 + 4] = c1;
  }
  __syncthreads();

  const int iS = tid >> 3, t7 = tid & 7;
  float dm[8] = {};
  for (int n8 = 0; n8 < 16; ++n8) {
    f32x4 cv0 = *(const f32x4*)&Cs[iS][n8 * 8];
    f32x4 cv1 = *(const f32x4*)&Cs[iS][n8 * 8 + 4];
#pragma unroll
    for (int q = 0; q < 8; ++q) {
      int j = t7 + q * 8;
      f32x4 bv0 = *(const f32x4*)&BsU[j][n8 * 8];
      f32x4 bv1 = *(const f32x4*)&BsU[j][n8 * 8 + 4];
      dm[q] += cv0[0] * bv0[0] + cv0[1] * bv0[1] + cv0[2] * bv0[2] + cv0[3] * bv0[3]
             + cv1[0] * bv1[0] + cv1[1] * bv1[1] + cv1[2] * bv1[2] + cv1[3] * bv1[3];
    }
  }
  __syncthreads();   // BsU region now free for Pt

  const int i0 = (tid >> 4) * 2;
  const int p0 = (tid & 15) * 4;

  for (int hh = 0; hh < 16; ++hh) {
    const int h = hbase + hh;
    const float Dh = Dv[h];
    const float negA = -expf(A_log[h]);

    const float* sb2 = states + ((long)gc * 64 + h) * 8192;
    f32x4 s0 = *(const f32x4*)(sb2 + tid * 4);
    f32x4 s1 = *(const f32x4*)(sb2 + 2048 + tid * 4);
    f32x4 s2 = *(const f32x4*)(sb2 + 4096 + tid * 4);
    f32x4 s3 = *(const f32x4*)(sb2 + 6144 + tid * 4);
    short8 x8 = *(const short8*)(proj + (rowbase + iS) * PROJ_N + h * 64 + t7 * 8);
    float d = dtbuf[(rowbase + lane) * 64 + h];

    float v = negA * d;
    {
      float t;
      t = __shfl_up(v, 1);  if (lane >= 1)  v += t;
      t = __shfl_up(v, 2);  if (lane >= 2)  v += t;
      t = __shfl_up(v, 4);  if (lane >= 4)  v += t;
      t = __shfl_up(v, 8);  if (lane >= 8)  v += t;
      t = __shfl_up(v, 16); if (lane >= 16) v += t;
      t = __shfl_up(v, 32); if (lane >= 32) v += t;
    }

    *(f32x4*)&Pt[tid * 4]        = s0;
    *(f32x4*)&Pt[2048 + tid * 4] = s1;
    *(f32x4*)&Pt[4096 + tid * 4] = s2;
    *(f32x4*)&Pt[6144 + tid * 4] = s3;
    *(short8*)&Xb[iS][t7 * 8] = x8;
    {
      const float ci = __shfl(v, iS);
#pragma unroll
      for (int q = 0; q < 8; ++q) {
        int j = t7 + q * 8;
        float cj = __shfl(v, j);
        float dj = __shfl(d, j);
        Scm[iS][j] = (j <= iS) ? dm[q] * expf(ci - cj) * dj : 0.f;
      }
    }
    __syncthreads();   // A: Pt, Xb, Scm ready

    const long r0w = rowbase + i0, r1w = r0w + 1;
    const long zo0 = r0w * 4096 + h * 64 + p0;
    const long zo1 = r1w * 4096 + h * 64 + p0;
    s16x4 zv0 = *(const s16x4*)&zio[zo0];
    s16x4 zv1 = *(const s16x4*)&zio[zo1];
    s16x4 xv0 = *(const s16x4*)(proj + r0w * PROJ_N + h * 64 + p0);
    s16x4 xv1 = *(const s16x4*)(proj + r1w * PROJ_N + h * 64 + p0);

    float ya0[4] = {}, ya1[4] = {};
#pragma unroll 4
    for (int j = 0; j < 64; ++j) {
      float sc0 = Scm[i0][j], sc1 = Scm[i0 + 1][j];
      s16x4 xj = *(const s16x4*)&Xb[j][p0];
#pragma unroll
      for (int k = 0; k < 4; ++k) {
        float xv = bf2f((unsigned short)xj[k]);
        ya0[k] += sc0 * xv;
        ya1[k] += sc1 * xv;
      }
    }
    float yb0[4] = {}, yb1[4] = {};
#pragma unroll 2
    for (int n8 = 0; n8 < 16; ++n8) {
      f32x4 ca0 = *(const f32x4*)&Cs[i0][n8 * 8];
      f32x4 ca1 = *(const f32x4*)&Cs[i0][n8 * 8 + 4];
      f32x4 cb0 = *(const f32x4*)&Cs[i0 + 1][n8 * 8];
      f32x4 cb1 = *(const f32x4*)&Cs[i0 + 1][n8 * 8 + 4];
#pragma unroll
      for (int q = 0; q < 8; ++q) {
        f32x4 pv = *(const f32x4*)&Pt[(n8 * 8 + q) * 64 + p0];
        float c0 = (q < 4) ? ca0[q] : ca1[q - 4];
        float c1 = (q < 4) ? cb0[q] : cb1[q - 4];
#pragma unroll
        for (int k = 0; k < 4; ++k) {
          yb0[k] += c0 * pv[k];
          yb1[k] += c1 * pv[k];
        }
      }
    }
    const float e0 = expf(__shfl(v, i0));
    const float e1 = expf(__shfl(v, i0 + 1));
    s16x4 o0, o1;
#pragma unroll
    for (int k = 0; k < 4; ++k) {
      float y = ya0[k] + e0 * yb0[k];
      float xraw = bf2f((unsigned short)xv0[k]);
      float zz = bf2f((unsigned short)zv0[k]);
      float sz = zz / (1.f + expf(-zz));
      o0[k] = (short)f2bf((y + xraw * Dh) * sz);
      y = ya1[k] + e1 * yb1[k];
      xraw = bf2f((unsigned short)xv1[k]);
      zz = bf2f((unsigned short)zv1[k]);
      sz = zz / (1.f + expf(-zz));
      o1[k] = (short)f2bf((y + xraw * Dh) * sz);
    }
    *(s16x4*)&zio[zo0] = o0;
    *(s16x4*)&zio[zo1] = o1;
    __syncthreads();   // B: LDS consumed, next head may overwrite
  }
}

// ---------- OLD serial SSD (fallback when workspace too small) ----------
__global__ __launch_bounds__(512) void ssd_gate_kernel(
    const unsigned short* __restrict__ proj,
    const float* __restrict__ dtbuf,
    const float* __restrict__ A_log,
    const float* __restrict__ Dv,
    unsigned short* __restrict__ zio) {
  __shared__ float st[64][128];
  __shared__ float Bs[64][128];
  __shared__ float Cs[64][128];
  __shared__ float Xs[64][64];
  __shared__ float Sc[64][64];
  __shared__ float cs[64];
  __shared__ float dtc[64];

  const int tid = threadIdx.x;
  const int bl = blockIdx.x >> 6;
  const int h = blockIdx.x & 63;
  const float negA = -expf(A_log[h]);
  const float Dh = Dv[h];

  for (int i = tid; i < 64 * 128; i += 512) (&st[0][0])[i] = 0.f;

  for (int c = 0; c < 64; ++c) {
    const long rowbase = (long)bl * LSEQ + c * 64;
    if (tid < 64) dtc[tid] = dtbuf[(rowbase + tid) * 64 + h];
    __syncthreads();
    if (tid == 0) {
      float run = 0.f;
      for (int j = 0; j < 64; ++j) { run += negA * dtc[j]; cs[j] = run; }
    }
    {
      const int j = tid >> 3;
      const int c8 = tid & 7;
      const unsigned short* rp = proj + (rowbase + j) * PROJ_N;
      const float dj = dtc[j];
#pragma unroll
      for (int q = 0; q < 8; ++q)
        Xs[j][c8 * 8 + q] = bf2f(rp[h * 64 + c8 * 8 + q]) * dj;
#pragma unroll
      for (int q = 0; q < 16; ++q) {
        Bs[j][c8 * 16 + q] = bf2f(rp[4160 + c8 * 16 + q]);
        Cs[j][c8 * 16 + q] = bf2f(rp[4288 + c8 * 16 + q]);
      }
    }
    __syncthreads();
    {
      const int i0 = (tid >> 4) * 2;
      const int j0 = (tid & 15) * 4;
      float a[2][4] = {};
      for (int n = 0; n < 128; ++n) {
        float c0 = Cs[i0][n], c1 = Cs[i0 + 1][n];
        float b0 = Bs[j0][n], b1 = Bs[j0 + 1][n], b2 = Bs[j0 + 2][n], b3 = Bs[j0 + 3][n];
        a[0][0] += c0 * b0; a[0][1] += c0 * b1; a[0][2] += c0 * b2; a[0][3] += c0 * b3;
        a[1][0] += c1 * b0; a[1][1] += c1 * b1; a[1][2] += c1 * b2; a[1][3] += c1 * b3;
      }
#pragma unroll
      for (int ii = 0; ii < 2; ++ii)
#pragma unroll
        for (int jj = 0; jj < 4; ++jj) {
          int i = i0 + ii, j = j0 + jj;
          Sc[i][j] = (j <= i) ? a[ii][jj] * expf(cs[i] - cs[j]) : 0.f;
        }
    }
    __syncthreads();
    {
      const int i0 = (tid >> 4) * 2;
      const int p0 = (tid & 15) * 4;
      float a1[2][4] = {};
      for (int j = 0; j < 64; ++j) {
        float s0 = Sc[i0][j], s1 = Sc[i0 + 1][j];
        float x0 = Xs[j][p0], x1 = Xs[j][p0 + 1], x2 = Xs[j][p0 + 2], x3 = Xs[j][p0 + 3];
        a1[0][0] += s0 * x0; a1[0][1] += s0 * x1; a1[0][2] += s0 * x2; a1[0][3] += s0 * x3;
        a1[1][0] += s1 * x0; a1[1][1] += s1 * x1; a1[1][2] += s1 * x2; a1[1][3] += s1 * x3;
      }
      float a2[2][4] = {};
      for (int n = 0; n < 128; ++n) {
        float c0 = Cs[i0][n], c1 = Cs[i0 + 1][n];
        float t0 = st[p0][n], t1 = st[p0 + 1][n], t2 = st[p0 + 2][n], t3 = st[p0 + 3][n];
        a2[0][0] += c0 * t0; a2[0][1] += c0 * t1; a2[0][2] += c0 * t2; a2[0][3] += c0 * t3;
        a2[1][0] += c1 * t0; a2[1][1] += c1 * t1; a2[1][2] += c1 * t2; a2[1][3] += c1 * t3;
      }
      float e0 = expf(cs[i0]), e1 = expf(cs[i0 + 1]);
#pragma unroll
      for (int ii = 0; ii < 2; ++ii) {
        const long r = rowbase + i0 + ii;
        const long zo = r * 4096 + h * 64 + p0;
        const unsigned short* xr = proj + r * PROJ_N + h * 64 + p0;
        float e = ii ? e1 : e0;
#pragma unroll
        for (int pp = 0; pp < 4; ++pp) {
          float y = a1[ii][pp] + e * a2[ii][pp];
          float xraw = bf2f(xr[pp]);
          float zz = bf2f(zio[zo + pp]);
          float sz = zz / (1.f + expf(-zz));
          zio[zo + pp] = f2bf((y + xraw * Dh) * sz);
        }
      }
    }
    __syncthreads();
    {
      const int j = tid >> 3;
      const int p0 = (tid & 7) * 8;
      float f = expf(cs[63] - cs[j]);
#pragma unroll
      for (int q = 0; q < 8; ++q) Xs[j][p0 + q] *= f;
    }
    __syncthreads();
    {
      const float dec = expf(cs[63]);
      const int p0 = (tid >> 5) * 4;
      const int n0 = (tid & 31) * 4;
      float a[4][4] = {};
      for (int j = 0; j < 64; ++j) {
        float x0 = Xs[j][p0], x1 = Xs[j][p0 + 1], x2 = Xs[j][p0 + 2], x3 = Xs[j][p0 + 3];
        float b0 = Bs[j][n0], b1 = Bs[j][n0 + 1], b2 = Bs[j][n0 + 2], b3 = Bs[j][n0 + 3];
        a[0][0] += x0 * b0; a[0][1] += x0 * b1; a[0][2] += x0 * b2; a[0][3] += x0 * b3;
        a[1][0] += x1 * b0; a[1][1] += x1 * b1; a[1][2] += x1 * b2; a[1][3] += x1 * b3;
        a[2][0] += x2 * b0; a[2][1] += x2 * b1; a[2][2] += x2 * b2; a[2][3] += x2 * b3;
        a[3][0] += x3 * b0; a[3][1] += x3 * b1; a[3][2] += x3 * b2; a[3][3] += x3 * b3;
      }
#pragma unroll
      for (int pp = 0; pp < 4; ++pp)
#pragma unroll
        for (int nn = 0; nn < 4; ++nn)
          st[p0 + pp][n0 + nn] = dec * st[p0 + pp][n0 + nn] + a[pp][nn];
    }
    __syncthreads();
  }
}

// ---------- launch ----------
extern "C" void kernel_launch(void* const* d_in, const int* in_sizes, int n_in,
                              void* d_out, int out_size, void* d_ws, size_t ws_size,
                              hipStream_t stream) {
  (void)in_sizes; (void)n_in; (void)out_size;
  const float* x    = (const float*)d_in[0];
  const float* w1   = (const float*)d_in[1]; // 8192 x 2048
  const float* cw   = (const float*)d_in[2]; // 4096 x 4
  const float* cb   = (const float*)d_in[3]; // 4096
  const float* w2   = (const float*)d_in[4]; // 4416 x 4096
  const float* dtw  = (const float*)d_in[5]; // 64 x 64
  const float* dtb  = (const float*)d_in[6]; // 64
  const float* Alog = (const float*)d_in[7]; // 64
  const float* Dv   = (const float*)d_in[8]; // 64
  const float* w3   = (const float*)d_in[9]; // 2048 x 4096
  float* out = (float*)d_out;

  const size_t NEED8 = 410025984ull;   // CR=8192 new path
  const size_t NEED4 = 205012992ull;   // CR=4096 new path
  int CR; bool newpath;
  if      (ws_size >= NEED8)               { CR = 8192; newpath = true;  }
  else if (ws_size >= NEED4)               { CR = 4096; newpath = true;  }
  else if (ws_size >= (size_t)8192 * 17280){ CR = 8192; newpath = false; }
  else if (ws_size >= (size_t)4096 * 17280){ CR = 4096; newpath = false; }
  else return;  // diagnostic: error == 8.69e-2 means ws too small

  char* w = (char*)d_ws;
  const size_t S1 = (size_t)CR * 4096 * 2;
  const size_t S2 = (size_t)CR * PROJ_N * 2;
  const int nb = CR / LSEQ;
  unsigned short* xc   = (unsigned short*)(w);       // conv out   [0, S1)
  unsigned short* xp   = (unsigned short*)(w + S1);  // pre-conv   (inside proj region)
  unsigned short* proj = (unsigned short*)(w + S1);  // x_proj out — over xp (dead)
  unsigned short* z    = (unsigned short*)(w);       // z branch — over xc (dead)
  float* dtf           = (float*)(w + S1 + S2);
  float* chdec         = (float*)(w + S1 + S2 + (size_t)CR * 256);
  float* states        = (float*)(w + S1 + S2 + (size_t)CR * 256 + (size_t)nb * 16384);

  // bf16 operand staging (inside states region — dead before ssd_states writes it)
  unsigned short* xbf  = (unsigned short*)states;            // CR x 2048
  unsigned short* w1bf = xbf + (size_t)CR * 2048;            // 8192 x 2048
  unsigned short* w2bf = w1bf + (size_t)8192 * 2048;         // 4416 x 4096
  unsigned short* w3bf = (unsigned short*)states;            // 2048 x 4096 (after ssd)

  for (int r0 = 0; r0 < 8192; r0 += CR) {
    const float* xr = x + (size_t)r0 * DMODEL;
    dim3 g1(DINNER / 128, CR / 128);
    dim3 g2((PROJ_N + 127) / 128, CR / 128);
    dim3 g3(DMODEL / 128, CR / 128);
    if (newpath) {
      // 0) convert x, w1, w2 to bf16 (RNE — bit-identical to previous on-the-fly path)
      f2bf_kernel<<<((long)CR * 2048 / 8 + 255) / 256, 256, 0, stream>>>(xr, xbf, (long)CR * 2048 / 8);
      f2bf_kernel<<<((long)8192 * 2048 / 8 + 255) / 256, 256, 0, stream>>>(w1, w1bf, (long)8192 * 2048 / 8);
      f2bf_kernel<<<((long)4416 * 4096 / 8 + 255) / 256, 256, 0, stream>>>(w2, w2bf, (long)4416 * 4096 / 8);
      // 1) in_proj x-half -> xp
      gemm_bb<true><<<g1, 256, 0, stream>>>(xbf, w1bf, xp, DMODEL, DINNER, DINNER);
      // 2) conv + silu -> xc
      conv_silu_kernel<<<((long)CR * 512) / 256, 256, 0, stream>>>(xp, cw, cb, xc, (long)CR * 512);
      // 3) x_proj -> proj
      gemm_bb<true><<<g2, 256, 0, stream>>>(xc, w2bf, proj, DINNER, PROJ_N, PROJ_N);
      // 4) dt
      dt_kernel<<<((long)CR * NHEADS) / 256, 256, 0, stream>>>(proj, dtw, dtb, dtf, (long)CR * NHEADS);
      // 5) in_proj z-half -> z
      gemm_bb<true><<<g1, 256, 0, stream>>>(xbf, w1bf + (size_t)DINNER * DMODEL, z, DMODEL, DINNER, DINNER);
      // 6) SSD + gate (states region overwrites xbf/w1bf/w2bf — all dead now)
      ssd_states_kernel<<<dim3(nb * 64, 64), 256, 0, stream>>>(proj, dtf, Alog, states, chdec);
      ssd_scan_kernel<<<dim3(32, nb * 64), 256, 0, stream>>>(states, chdec);
      ssd_ydo_gate_kernel<<<dim3(nb * 64, 4), 512, 0, stream>>>(proj, dtf, Alog, Dv, states, z);
      // 7) out_proj (w3 converted after states is dead, into states region)
      f2bf_kernel<<<((long)2048 * 4096 / 8 + 255) / 256, 256, 0, stream>>>(w3, w3bf, (long)2048 * 4096 / 8);
      gemm_bb<false><<<g3, 256, 0, stream>>>(z, w3bf, out + (size_t)r0 * DMODEL, DINNER, DMODEL, DMODEL);
    } else {
      gemm_nt<true, true><<<g1, 256, 0, stream>>>(xr, w1, xp, DMODEL, DINNER, DINNER);
      conv_silu_kernel<<<((long)CR * 512) / 256, 256, 0, stream>>>(xp, cw, cb, xc, (long)CR * 512);
      gemm_nt<false, true><<<g2, 256, 0, stream>>>(xc, w2, proj, DINNER, PROJ_N, PROJ_N);
      dt_kernel<<<((long)CR * NHEADS) / 256, 256, 0, stream>>>(proj, dtw, dtb, dtf, (long)CR * NHEADS);
      gemm_nt<true, true><<<g1, 256, 0, stream>>>(xr, w1 + (size_t)DINNER * DMODEL, z, DMODEL, DINNER, DINNER);
      ssd_gate_kernel<<<(CR / LSEQ) * NHEADS, 512, 0, stream>>>(proj, dtf, Alog, Dv, z);
      gemm_nt<false, false><<<g3, 256, 0, stream>>>(z, w3, out + (size_t)r0 * DMODEL, DINNER, DMODEL, DMODEL);
    }
  }
}

// Round 6
// 1920.767 us; speedup vs baseline: 4.0476x; 1.1223x over previous
//
#include <hip/hip_runtime.h>

// ---------- types / helpers ----------
typedef __attribute__((ext_vector_type(8))) short short8;
typedef __attribute__((ext_vector_type(4))) short s16x4;
typedef __attribute__((ext_vector_type(4))) float f32x4;
typedef __attribute__((ext_vector_type(4))) unsigned int u32x4;

typedef __attribute__((address_space(3))) unsigned int lds_u32;
typedef __attribute__((address_space(1))) unsigned int glob_u32;

__device__ __forceinline__ float bf2f(unsigned short s) {
  unsigned int v = ((unsigned int)s) << 16; float f; __builtin_memcpy(&f, &v, 4); return f;
}
__device__ __forceinline__ unsigned short f2bf(float f) {
  unsigned int u; __builtin_memcpy(&u, &f, 4);
  u += 0x7fffu + ((u >> 16) & 1u);   // RNE (finite values only here)
  return (unsigned short)(u >> 16);
}
__device__ __forceinline__ unsigned int pack2bf(float lo, float hi) {
  return (unsigned int)f2bf(lo) | ((unsigned int)f2bf(hi) << 16);
}
__device__ __forceinline__ u32x4 pack8bf(f32x4 a, f32x4 b) {
  u32x4 r;
  r[0] = pack2bf(a[0], a[1]);
  r[1] = pack2bf(a[2], a[3]);
  r[2] = pack2bf(b[0], b[1]);
  r[3] = pack2bf(b[2], b[3]);
  return r;
}
__device__ __forceinline__ void ld8bf(const unsigned short* p, float* o) {
  short8 v = *(const short8*)p;
#pragma unroll
  for (int q = 0; q < 8; ++q) o[q] = bf2f((unsigned short)v[q]);
}
// async global->LDS, 16B per lane. LDS dest: wave-uniform base + lane*16.
__device__ __forceinline__ void gl2lds16(const unsigned short* g, unsigned short* l) {
  __builtin_amdgcn_global_load_lds((const glob_u32*)g, (lds_u32*)l, 16, 0, 0);
}

// ---------- constants ----------
#define LSEQ   4096
#define DMODEL 2048
#define DINNER 4096
#define NHEADS 64
#define PROJ_N 4416    // D_INNER + NHEADS + 2*D_STATE

// ---------- fp32 -> bf16 bulk convert (RNE, identical to pack8bf path) ----------
__global__ void f2bf_kernel(const float* __restrict__ in, unsigned short* __restrict__ out, long n8) {
  long i = (long)blockIdx.x * blockDim.x + threadIdx.x;
  if (i >= n8) return;
  f32x4 a = *(const f32x4*)(in + i * 8);
  f32x4 b = *(const f32x4*)(in + i * 8 + 4);
  *(u32x4*)(out + i * 8) = pack8bf(a, b);
}

// ==================================================================
// 256x256 8-phase bf16 GEMM (T2+T3+T4+T5): C[m][n] = sum_k A[m][k]*B[n][k]
// BK=64, 512 thr (2x4 waves), 128 KiB LDS dbuf, counted vmcnt(4) at ph4/ph8,
// st-swizzle via pre-swizzled global source + XOR'd ds_read (rule #21).
// ==================================================================
#define CFENCE asm volatile("" ::: "memory")
#define BARRIER do { CFENCE; __builtin_amdgcn_s_barrier(); CFENCE; } while (0)
#define VMW(n) asm volatile("s_waitcnt vmcnt(" #n ")" ::: "memory")

template <int MODE>   // 0: bf16 out, 1: fp32 out
__global__ __launch_bounds__(512, 2) void gemm256(
    const unsigned short* __restrict__ A,   // M x K bf16 row-major
    const unsigned short* __restrict__ B,   // nmax x K bf16 row-major (rows clamped)
    void* __restrict__ Cp, int K, int ldc, int nmax) {
  __shared__ __attribute__((aligned(16))) char smem[131072];
  const int tid = threadIdx.x;
  // XCD-aware chunked swizzle (all grids used are %8 == 0)
  const int nbx = gridDim.x;
  int flat = blockIdx.y * nbx + blockIdx.x;
  const int nwg = nbx * gridDim.y;
  if ((nwg & 7) == 0) { const int cpx = nwg >> 3; flat = (flat & 7) * cpx + (flat >> 3); }
  const int m0 = (flat / nbx) * 256;
  const int n0 = (flat % nbx) * 256;

  const int wave = tid >> 6, lane = tid & 63;
  const int wm = wave >> 2;            // 0..1  (128 M-rows per wave)
  const int wn = wave & 3;             // 0..3  (64 N-cols per wave)
  const int quad = lane >> 4, l16 = lane & 15;

  // ---- staging addressing: linear LDS dest, inverse-swizzled global source ----
  const int r0 = tid >> 3;                       // 0..63 (row within 64-row sweep)
  const int kboff = ((tid & 7) ^ (r0 & 7)) * 8;  // element offset in 64-elem K-chunk
  const long lK = K;
  const unsigned short* pa[4];
  const unsigned short* pb[4];
#pragma unroll
  for (int h2 = 0; h2 < 4; ++h2) {
    pa[h2] = A + (long)(m0 + h2 * 64 + r0) * lK + kboff;
    int br = n0 + h2 * 64 + r0; if (br > nmax - 1) br = nmax - 1;
    pb[h2] = B + (long)br * lK + kboff;
  }
  char* ldsp = (char*)smem;
  const int ldst = tid * 16;

  // buf b: A at b*65536 (32KB), B at b*65536 + 32768 (32KB)
#define STG_A(b, h, kt) do { \
    gl2lds16(pa[(h)*2]     + (long)(kt) * 64, (unsigned short*)(ldsp + (b)*65536 + (h)*16384 + ldst)); \
    gl2lds16(pa[(h)*2 + 1] + (long)(kt) * 64, (unsigned short*)(ldsp + (b)*65536 + (h)*16384 + 8192 + ldst)); \
  } while (0)
#define STG_B(b, h, kt) do { \
    gl2lds16(pb[(h)*2]     + (long)(kt) * 64, (unsigned short*)(ldsp + (b)*65536 + 32768 + (h)*16384 + ldst)); \
    gl2lds16(pb[(h)*2 + 1] + (long)(kt) * 64, (unsigned short*)(ldsp + (b)*65536 + 32768 + (h)*16384 + 8192 + ldst)); \
  } while (0)

  // ---- ds_read addressing (XOR swizzle on column byte) ----
  const int xm = (l16 & 7) << 4;
  const int cb0 = (quad * 16) ^ xm;    // ks = 0
  const int cb1 = cb0 ^ 64;            // ks = 1
  const int aoff = (wm * 128 + l16) * 128;          // + mq*4096 + mr*2048 + cb
  const int boff = 32768 + (wn * 64 + l16) * 128;   // + nr*2048 + cb

  f32x4 acc[8][4];
  {
    f32x4 z4 = {0.f, 0.f, 0.f, 0.f};
#pragma unroll
    for (int i = 0; i < 8; ++i)
#pragma unroll
      for (int j = 0; j < 4; ++j) acc[i][j] = z4;
  }
  short8 afr[2][2], bfr[4][2];

#define LDB(b) do { \
    const char* p_ = ldsp + (b) * 65536 + boff; \
    _Pragma("unroll") for (int nr = 0; nr < 4; ++nr) { \
      bfr[nr][0] = *(const short8*)(p_ + nr * 2048 + cb0); \
      bfr[nr][1] = *(const short8*)(p_ + nr * 2048 + cb1); } \
  } while (0)
#define LDA(b, mq) do { \
    const char* p_ = ldsp + (b) * 65536 + aoff + (mq) * 4096; \
    _Pragma("unroll") for (int mr = 0; mr < 2; ++mr) { \
      afr[mr][0] = *(const short8*)(p_ + mr * 2048 + cb0); \
      afr[mr][1] = *(const short8*)(p_ + mr * 2048 + cb1); } \
  } while (0)
#define MM(mq) do { \
    __builtin_amdgcn_s_setprio(1); \
    _Pragma("unroll") for (int ks = 0; ks < 2; ++ks) \
    _Pragma("unroll") for (int mr = 0; mr < 2; ++mr) \
    _Pragma("unroll") for (int nr = 0; nr < 4; ++nr) \
      acc[(mq) * 2 + mr][nr] = __builtin_amdgcn_mfma_f32_16x16x32_bf16( \
          afr[mr][ks], bfr[nr][ks], acc[(mq) * 2 + mr][nr], 0, 0, 0); \
    __builtin_amdgcn_s_setprio(0); \
  } while (0)

  const int nt = K >> 6;   // K-tiles (even for all our shapes)

  // ---- prologue: A(0),B(0)->buf0, B(1)->buf1; drain; barrier ----
  STG_A(0, 0, 0); STG_A(0, 1, 0);
  STG_B(0, 0, 0); STG_B(0, 1, 0);
  STG_B(1, 0, 1); STG_B(1, 1, 1);
  VMW(0);
  BARRIER;

  for (int t = 0; t < nt; t += 2) {
    const int kt1 = t + 1;
    const int kt2 = (t + 2 < nt) ? t + 2 : nt - 1;   // clamped (tail stages unread)
    const int kt3 = (t + 3 < nt) ? t + 3 : nt - 1;
    // ph1: reads buf0 B + A-q0; stage A(t+1)->buf1 (freed end of prev ph8)
    LDB(0); LDA(0, 0);
    STG_A(1, 0, kt1); STG_A(1, 1, kt1);
    BARRIER; MM(0); BARRIER;
    // ph2: A-q1; stage Bh0(t+2)->buf0.B (freed end of ph1)
    LDA(0, 1); STG_B(0, 0, kt2);
    BARRIER; MM(1); BARRIER;
    // ph3: A-q2; stage Bh1(t+2)
    LDA(0, 2); STG_B(0, 1, kt2);
    BARRIER; MM(2); BARRIER;
    // ph4: A-q3; vmcnt(4) keeps only B(t+2) in flight -> A(t+1),B(t+1) landed
    LDA(0, 3);
    BARRIER; MM(3); VMW(4); BARRIER;
    // ph5: reads buf1 B + A-q0; stage Ah0(t+2)->buf0.A (freed end of ph4)
    LDB(1); LDA(1, 0);
    STG_A(0, 0, kt2);
    BARRIER; MM(0); BARRIER;
    // ph6: A-q1; stage Ah1(t+2)
    LDA(1, 1); STG_A(0, 1, kt2);
    BARRIER; MM(1); BARRIER;
    // ph7: A-q2; stage Bh0(t+3)->buf1.B (freed end of ph5)
    LDA(1, 2); STG_B(1, 0, kt3);
    BARRIER; MM(2); BARRIER;
    // ph8: A-q3; vmcnt(4) keeps only B(t+3) in flight -> A(t+2),B(t+2) landed
    LDA(1, 3); STG_B(1, 1, kt3);
    BARRIER; MM(3); VMW(4); BARRIER;
  }

  // ---- epilogue ----
#pragma unroll
  for (int i = 0; i < 8; ++i) {
    const int mbase = m0 + wm * 128 + i * 16 + quad * 4;
#pragma unroll
    for (int j = 0; j < 4; ++j) {
      const int n = n0 + wn * 64 + j * 16 + l16;
      if (n < nmax) {
#pragma unroll
        for (int r = 0; r < 4; ++r) {
          const long o = (long)(mbase + r) * ldc + n;
          if (MODE == 0) ((unsigned short*)Cp)[o] = f2bf(acc[i][j][r]);
          else           ((float*)Cp)[o] = acc[i][j][r];
        }
      }
    }
  }
#undef STG_A
#undef STG_B
#undef LDB
#undef LDA
#undef MM
}

// ---------- legacy mixed GEMM (fallback path only) ----------
template <bool A_F32, bool OUT_BF16>
__global__ __launch_bounds__(256) void gemm_nt(
    const void* __restrict__ Ap,
    const float* __restrict__ B,
    void* __restrict__ Cp, int K, int ldc, int nmax) {
  __shared__ __attribute__((aligned(16))) unsigned short Asm[128 * 32];
  __shared__ __attribute__((aligned(16))) unsigned short Bsm[128 * 32];
  const int tid = threadIdx.x;
  const int m0 = blockIdx.y * 128;
  const int n0 = blockIdx.x * 128;
  const int wave = tid >> 6, lane = tid & 63;
  const int wm = (wave >> 1) * 64, wn = (wave & 1) * 64;
  const int quad = lane >> 4, l16 = lane & 15;
  const int rowL = tid >> 2;
  const int kk = (tid & 3) * 8;
  const long lK = K;

  int rb0 = n0 + rowL;      if (rb0 > nmax - 1) rb0 = nmax - 1;
  int rb1 = n0 + rowL + 64; if (rb1 > nmax - 1) rb1 = nmax - 1;

  f32x4 zero = {0.f, 0.f, 0.f, 0.f};
  f32x4 acc[4][4];
#pragma unroll
  for (int i = 0; i < 4; ++i)
#pragma unroll
    for (int j = 0; j < 4; ++j) acc[i][j] = zero;

  for (int kt = 0; kt < K; kt += 32) {
    const float* pb0 = B + (long)rb0 * lK + kt + kk;
    const float* pb1 = B + (long)rb1 * lK + kt + kk;
    f32x4 b00 = *(const f32x4*)pb0;
    f32x4 b01 = *(const f32x4*)(pb0 + 4);
    f32x4 b10 = *(const f32x4*)pb1;
    f32x4 b11 = *(const f32x4*)(pb1 + 4);
    u32x4 bw0 = pack8bf(b00, b01);
    u32x4 bw1 = pack8bf(b10, b11);
    u32x4 aw0, aw1;
    if (A_F32) {
      const float* pa = (const float*)Ap + (long)(m0 + rowL) * lK + kt + kk;
      f32x4 a00 = *(const f32x4*)pa;
      f32x4 a01 = *(const f32x4*)(pa + 4);
      f32x4 a10 = *(const f32x4*)(pa + 64 * lK);
      f32x4 a11 = *(const f32x4*)(pa + 64 * lK + 4);
      aw0 = pack8bf(a00, a01);
      aw1 = pack8bf(a10, a11);
    } else {
      const unsigned short* pa = (const unsigned short*)Ap + (long)(m0 + rowL) * lK + kt + kk;
      aw0 = *(const u32x4*)pa;
      aw1 = *(const u32x4*)(pa + 64 * lK);
    }
    *(u32x4*)(Asm + tid * 8) = aw0;
    *(u32x4*)(Asm + tid * 8 + 2048) = aw1;
    *(u32x4*)(Bsm + tid * 8) = bw0;
    *(u32x4*)(Bsm + tid * 8 + 2048) = bw1;
    __syncthreads();
    short8 af[4], bfv[4];
#pragma unroll
    for (int i = 0; i < 4; ++i) {
      af[i]  = *(const short8*)(Asm + (wm + i * 16 + l16) * 32 + quad * 8);
      bfv[i] = *(const short8*)(Bsm + (wn + i * 16 + l16) * 32 + quad * 8);
    }
#pragma unroll
    for (int i = 0; i < 4; ++i)
#pragma unroll
      for (int j = 0; j < 4; ++j)
        acc[i][j] = __builtin_amdgcn_mfma_f32_16x16x32_bf16(af[i], bfv[j], acc[i][j], 0, 0, 0);
    __syncthreads();
  }

#pragma unroll
  for (int i = 0; i < 4; ++i) {
    const int mbase = m0 + wm + i * 16 + quad * 4;
#pragma unroll
    for (int j = 0; j < 4; ++j) {
      const int n = n0 + wn + j * 16 + l16;
      if (n < nmax) {
#pragma unroll
        for (int r = 0; r < 4; ++r) {
          const long o = (long)(mbase + r) * ldc + n;
          if (OUT_BF16) ((unsigned short*)Cp)[o] = f2bf(acc[i][j][r]);
          else          ((float*)Cp)[o] = acc[i][j][r];
        }
      }
    }
  }
}

// ---------- depthwise causal conv (taps=4) + bias + silu, vectorized 8ch/thread ----------
__global__ void conv_silu_kernel(const unsigned short* __restrict__ xin,
                                 const float* __restrict__ cw,
                                 const float* __restrict__ cb,
                                 unsigned short* __restrict__ xout, long nv) {
  long idx = (long)blockIdx.x * blockDim.x + threadIdx.x; // rows*512
  if (idx >= nv) return;
  int c8 = (int)(idx & 511);
  long row = idx >> 9;
  int l = (int)(row & (LSEQ - 1));
  int ch0 = c8 * 8;
  float acc[8];
#pragma unroll
  for (int q = 0; q < 8; ++q) acc[q] = cb[ch0 + q];
#pragma unroll
  for (int t = 0; t < 4; ++t) {
    int ll = l - 3 + t;
    if (ll >= 0) {
      float f[8];
      ld8bf(xin + (row - 3 + t) * 4096 + ch0, f);
#pragma unroll
      for (int q = 0; q < 8; ++q) acc[q] += f[q] * cw[(ch0 + q) * 4 + t];
    }
  }
  short8 o;
#pragma unroll
  for (int q = 0; q < 8; ++q) {
    float a = acc[q] / (1.f + expf(-acc[q]));
    o[q] = (short)f2bf(a);
  }
  *(short8*)(xout + row * 4096 + ch0) = o;
}

// ---------- dt: softplus(dt_in @ dtW^T + dtb) -> fp32 ----------
__global__ void dt_kernel(const unsigned short* __restrict__ proj,
                          const float* __restrict__ dtw,
                          const float* __restrict__ dtb,
                          float* __restrict__ dt, long n) {
  long idx = (long)blockIdx.x * blockDim.x + threadIdx.x; // rows*64
  if (idx >= n) return;
  int h = (int)(idx & 63);
  long row = idx >> 6;
  const unsigned short* p = proj + row * PROJ_N + DINNER;
  float s = dtb[h];
#pragma unroll
  for (int k8 = 0; k8 < 8; ++k8) {
    float f[8];
    ld8bf(p + k8 * 8, f);
    const float* wv = dtw + h * 64 + k8 * 8;
#pragma unroll
    for (int q = 0; q < 8; ++q) s += f[q] * wv[q];
  }
  dt[idx] = (s > 20.f) ? s : log1pf(expf(s));
}

// ==================================================================
// Parallel chunked SSD (3 kernels)
// states layout (TRANSPOSED): states[(gc*64 + h)*8192 + n*64 + p], gc = b*64 + c
// ==================================================================

__global__ __launch_bounds__(256) void ssd_states_kernel(
    const unsigned short* __restrict__ proj,
    const float* __restrict__ dtbuf,
    const float* __restrict__ A_log,
    float* __restrict__ states,
    float* __restrict__ chdec) {
  __shared__ float Bs[64][132];
  __shared__ float Xw[64][68];
  __shared__ float csh[64];
  __shared__ float dth[64];
  const int tid = threadIdx.x;
  const int gc = blockIdx.x;       // b*64 + c
  const int h  = blockIdx.y;
  const long rowbase = (long)gc * 64;

  const float negA = -expf(A_log[h]);
  if (tid < 64) {
    float d = dtbuf[(rowbase + tid) * 64 + h];
    float v = negA * d;
#pragma unroll
    for (int off = 1; off < 64; off <<= 1) {
      float t = __shfl_up(v, off);
      if (tid >= off) v += t;
    }
    csh[tid] = v;
    dth[tid] = d;
  }
  __syncthreads();
  const float cs63 = csh[63];

  for (int idx = tid; idx < 64 * 16; idx += 256) {
    int r = idx >> 4, c8 = idx & 15;
    float f[8];
    ld8bf(proj + (rowbase + r) * PROJ_N + 4160 + c8 * 8, f);
#pragma unroll
    for (int q = 0; q < 8; ++q) Bs[r][c8 * 8 + q] = f[q];
  }
  for (int idx = tid; idx < 64 * 8; idx += 256) {
    int r = idx >> 3, c8 = idx & 7;
    float f[8];
    ld8bf(proj + (rowbase + r) * PROJ_N + h * 64 + c8 * 8, f);
    float w = dth[r] * expf(cs63 - csh[r]);
#pragma unroll
    for (int q = 0; q < 8; ++q) Xw[r][c8 * 8 + q] = w * f[q];
  }
  __syncthreads();

  const int p0 = (tid >> 4) * 4;
  const int n0 = (tid & 15) * 4;
  float a0[4][4] = {};
  float a1[4][4] = {};
  for (int j = 0; j < 64; ++j) {
    f32x4 xv = *(const f32x4*)&Xw[j][p0];
    f32x4 b0 = *(const f32x4*)&Bs[j][n0];
    f32x4 b1 = *(const f32x4*)&Bs[j][n0 + 64];
#pragma unroll
    for (int pp = 0; pp < 4; ++pp)
#pragma unroll
      for (int q = 0; q < 4; ++q) {
        a0[pp][q] += xv[pp] * b0[q];
        a1[pp][q] += xv[pp] * b1[q];
      }
  }
  float* sb = states + ((long)gc * 64 + h) * 8192;
#pragma unroll
  for (int q = 0; q < 4; ++q) {
    f32x4 t0, t1;
#pragma unroll
    for (int pp = 0; pp < 4; ++pp) { t0[pp] = a0[pp][q]; t1[pp] = a1[pp][q]; }
    *(f32x4*)(sb + (n0 + q) * 64 + p0) = t0;
    *(f32x4*)(sb + (n0 + 64 + q) * 64 + p0) = t1;
  }
  if (tid == 0) chdec[gc * 64 + h] = expf(cs63);
}

__global__ __launch_bounds__(256) void ssd_scan_kernel(
    float* __restrict__ states, const float* __restrict__ chdec) {
  const int by = blockIdx.y;            // b*64 + h
  const int b = by >> 6, h = by & 63;
  const int pn = blockIdx.x * 256 + threadIdx.x;   // 0..8191
  float P = 0.f;
  long base = ((long)b * 64 * 64 + h) * 8192 + pn;
  for (int c = 0; c < 64; ++c) {
    long o = base + (long)c * (64 * 8192);
    float S = states[o];
    states[o] = P;
    P = chdec[(b * 64 + c) * 64 + h] * P + S;
  }
}

// ---- phase 3: Y = Sc @ (dt*X) + exp(cs_i) * (C @ P^T), + D-residual, * silu(z), in place
__global__ __launch_bounds__(512, 4) void ssd_ydo_gate_kernel(
    const unsigned short* __restrict__ proj,
    const float* __restrict__ dtbuf,
    const float* __restrict__ A_log,
    const float* __restrict__ Dv,
    const float* __restrict__ states,
    unsigned short* __restrict__ zio) {
  __shared__ __attribute__((aligned(16))) char smem[76800];
  float (*Cs)[68]          = (float(*)[68])(smem);             // 17408 B, fp32 C
  float (*Scm)[68]         = (float(*)[68])(smem + 17408);     // 17408 B, scores
  unsigned short (*Xb)[72] = (unsigned short(*)[72])(smem + 34816); // 9216 B, raw X bf16
  float* Pt                = (float*)(smem + 44032);           // 32768 B, state [n][p]
  float (*BsU)[68]         = (float(*)[68])(smem + 44032);     // union: B fp32 (Dm build only)

  const int tid = threadIdx.x;
  const int lane = tid & 63;
  const int gc = blockIdx.x;
  const int hbase = blockIdx.y * 16;
  const long rowbase = (long)gc * 64;

#pragma unroll
  for (int k = 0; k < 2; ++k) {
    int idx = tid + k * 512;
    int r = idx >> 4, c8 = idx & 15;
    const unsigned short* rp = proj + (rowbase + r) * PROJ_N;
    float fB[8], fC[8];
    ld8bf(rp + 4160 + c8 * 8, fB);
    ld8bf(rp + 4288 + c8 * 8, fC);
    f32x4 b0, b1, c0, c1;
#pragma unroll
    for (int q = 0; q < 4; ++q) { b0[q] = fB[q]; b1[q] = fB[q + 4]; c0[q] = fC[q]; c1[q] = fC[q + 4]; }
    *(f32x4*)&BsU[r][c8 * 8] = b0;
    *(f32x4*)&BsU[r][c8 * 8 + 4] = b1;
    *(f32x4*)&Cs[r][c8 * 8] = c0;
    *(f32x4*)&Cs[r][c8 * 8 + 4] = c1;
  }
  __syncthreads();

  const int iS = tid >> 3, t7 = tid & 7;
  float dm[8] = {};
  for (int n8 = 0; n8 < 16; ++n8) {
    f32x4 cv0 = *(const f32x4*)&Cs[iS][n8 * 8];
    f32x4 cv1 = *(const f32x4*)&Cs[iS][n8 * 8 + 4];
#pragma unroll
    for (int q = 0; q < 8; ++q) {
      int j = t7 + q * 8;
      f32x4 bv0 = *(const f32x4*)&BsU[j][n8 * 8];
      f32x4 bv1 = *(const f32x4*)&BsU[j][n8 * 8 + 4];
      dm[q] += cv0[0] * bv0[0] + cv0[1] * bv0[1] + cv0[2] * bv0[2] + cv0[3] * bv0[3]
             + cv1[0] * bv1[0] + cv1[1] * bv1[1] + cv1[2] * bv1[2] + cv1[3] * bv1[3];
    }
  }
  __syncthreads();   // BsU region now free for Pt

  const int i0 = (tid >> 4) * 2;
  const int p0 = (tid & 15) * 4;

  for (int hh = 0; hh < 16; ++hh) {
    const int h = hbase + hh;
    const float Dh = Dv[h];
    const float negA = -expf(A_log[h]);

    const float* sb2 = states + ((long)gc * 64 + h) * 8192;
    f32x4 s0 = *(const f32x4*)(sb2 + tid * 4);
    f32x4 s1 = *(const f32x4*)(sb2 + 2048 + tid * 4);
    f32x4 s2 = *(const f32x4*)(sb2 + 4096 + tid * 4);
    f32x4 s3 = *(const f32x4*)(sb2 + 6144 + tid * 4);
    short8 x8 = *(const short8*)(proj + (rowbase + iS) * PROJ_N + h * 64 + t7 * 8);
    float d = dtbuf[(rowbase + lane) * 64 + h];

    float v = negA * d;
    {
      float t;
      t = __shfl_up(v, 1);  if (lane >= 1)  v += t;
      t = __shfl_up(v, 2);  if (lane >= 2)  v += t;
      t = __shfl_up(v, 4);  if (lane >= 4)  v += t;
      t = __shfl_up(v, 8);  if (lane >= 8)  v += t;
      t = __shfl_up(v, 16); if (lane >= 16) v += t;
      t = __shfl_up(v, 32); if (lane >= 32) v += t;
    }

    *(f32x4*)&Pt[tid * 4]        = s0;
    *(f32x4*)&Pt[2048 + tid * 4] = s1;
    *(f32x4*)&Pt[4096 + tid * 4] = s2;
    *(f32x4*)&Pt[6144 + tid * 4] = s3;
    *(short8*)&Xb[iS][t7 * 8] = x8;
    {
      const float ci = __shfl(v, iS);
#pragma unroll
      for (int q = 0; q < 8; ++q) {
        int j = t7 + q * 8;
        float cj = __shfl(v, j);
        float dj = __shfl(d, j);
        Scm[iS][j] = (j <= iS) ? dm[q] * expf(ci - cj) * dj : 0.f;
      }
    }
    __syncthreads();   // A: Pt, Xb, Scm ready

    const long r0w = rowbase + i0, r1w = r0w + 1;
    const long zo0 = r0w * 4096 + h * 64 + p0;
    const long zo1 = r1w * 4096 + h * 64 + p0;
    s16x4 zv0 = *(const s16x4*)&zio[zo0];
    s16x4 zv1 = *(const s16x4*)&zio[zo1];
    s16x4 xv0 = *(const s16x4*)(proj + r0w * PROJ_N + h * 64 + p0);
    s16x4 xv1 = *(const s16x4*)(proj + r1w * PROJ_N + h * 64 + p0);

    float ya0[4] = {}, ya1[4] = {};
#pragma unroll 4
    for (int j = 0; j < 64; ++j) {
      float sc0 = Scm[i0][j], sc1 = Scm[i0 + 1][j];
      s16x4 xj = *(const s16x4*)&Xb[j][p0];
#pragma unroll
      for (int k = 0; k < 4; ++k) {
        float xv = bf2f((unsigned short)xj[k]);
        ya0[k] += sc0 * xv;
        ya1[k] += sc1 * xv;
      }
    }
    float yb0[4] = {}, yb1[4] = {};
#pragma unroll 2
    for (int n8 = 0; n8 < 16; ++n8) {
      f32x4 ca0 = *(const f32x4*)&Cs[i0][n8 * 8];
      f32x4 ca1 = *(const f32x4*)&Cs[i0][n8 * 8 + 4];
      f32x4 cb0 = *(const f32x4*)&Cs[i0 + 1][n8 * 8];
      f32x4 cb1 = *(const f32x4*)&Cs[i0 + 1][n8 * 8 + 4];
#pragma unroll
      for (int q = 0; q < 8; ++q) {
        f32x4 pv = *(const f32x4*)&Pt[(n8 * 8 + q) * 64 + p0];
        float c0 = (q < 4) ? ca0[q] : ca1[q - 4];
        float c1 = (q < 4) ? cb0[q] : cb1[q - 4];
#pragma unroll
        for (int k = 0; k < 4; ++k) {
          yb0[k] += c0 * pv[k];
          yb1[k] += c1 * pv[k];
        }
      }
    }
    const float e0 = expf(__shfl(v, i0));
    const float e1 = expf(__shfl(v, i0 + 1));
    s16x4 o0, o1;
#pragma unroll
    for (int k = 0; k < 4; ++k) {
      float y = ya0[k] + e0 * yb0[k];
      float xraw = bf2f((unsigned short)xv0[k]);
      float zz = bf2f((unsigned short)zv0[k]);
      float sz = zz / (1.f + expf(-zz));
      o0[k] = (short)f2bf((y + xraw * Dh) * sz);
      y = ya1[k] + e1 * yb1[k];
      xraw = bf2f((unsigned short)xv1[k]);
      zz = bf2f((unsigned short)zv1[k]);
      sz = zz / (1.f + expf(-zz));
      o1[k] = (short)f2bf((y + xraw * Dh) * sz);
    }
    *(s16x4*)&zio[zo0] = o0;
    *(s16x4*)&zio[zo1] = o1;
    __syncthreads();   // B: LDS consumed, next head may overwrite
  }
}

// ---------- OLD serial SSD (fallback when workspace too small) ----------
__global__ __launch_bounds__(512) void ssd_gate_kernel(
    const unsigned short* __restrict__ proj,
    const float* __restrict__ dtbuf,
    const float* __restrict__ A_log,
    const float* __restrict__ Dv,
    unsigned short* __restrict__ zio) {
  __shared__ float st[64][128];
  __shared__ float Bs[64][128];
  __shared__ float Cs[64][128];
  __shared__ float Xs[64][64];
  __shared__ float Sc[64][64];
  __shared__ float cs[64];
  __shared__ float dtc[64];

  const int tid = threadIdx.x;
  const int bl = blockIdx.x >> 6;
  const int h = blockIdx.x & 63;
  const float negA = -expf(A_log[h]);
  const float Dh = Dv[h];

  for (int i = tid; i < 64 * 128; i += 512) (&st[0][0])[i] = 0.f;

  for (int c = 0; c < 64; ++c) {
    const long rowbase = (long)bl * LSEQ + c * 64;
    if (tid < 64) dtc[tid] = dtbuf[(rowbase + tid) * 64 + h];
    __syncthreads();
    if (tid == 0) {
      float run = 0.f;
      for (int j = 0; j < 64; ++j) { run += negA * dtc[j]; cs[j] = run; }
    }
    {
      const int j = tid >> 3;
      const int c8 = tid & 7;
      const unsigned short* rp = proj + (rowbase + j) * PROJ_N;
      const float dj = dtc[j];
#pragma unroll
      for (int q = 0; q < 8; ++q)
        Xs[j][c8 * 8 + q] = bf2f(rp[h * 64 + c8 * 8 + q]) * dj;
#pragma unroll
      for (int q = 0; q < 16; ++q) {
        Bs[j][c8 * 16 + q] = bf2f(rp[4160 + c8 * 16 + q]);
        Cs[j][c8 * 16 + q] = bf2f(rp[4288 + c8 * 16 + q]);
      }
    }
    __syncthreads();
    {
      const int i0 = (tid >> 4) * 2;
      const int j0 = (tid & 15) * 4;
      float a[2][4] = {};
      for (int n = 0; n < 128; ++n) {
        float c0 = Cs[i0][n], c1 = Cs[i0 + 1][n];
        float b0 = Bs[j0][n], b1 = Bs[j0 + 1][n], b2 = Bs[j0 + 2][n], b3 = Bs[j0 + 3][n];
        a[0][0] += c0 * b0; a[0][1] += c0 * b1; a[0][2] += c0 * b2; a[0][3] += c0 * b3;
        a[1][0] += c1 * b0; a[1][1] += c1 * b1; a[1][2] += c1 * b2; a[1][3] += c1 * b3;
      }
#pragma unroll
      for (int ii = 0; ii < 2; ++ii)
#pragma unroll
        for (int jj = 0; jj < 4; ++jj) {
          int i = i0 + ii, j = j0 + jj;
          Sc[i][j] = (j <= i) ? a[ii][jj] * expf(cs[i] - cs[j]) : 0.f;
        }
    }
    __syncthreads();
    {
      const int i0 = (tid >> 4) * 2;
      const int p0 = (tid & 15) * 4;
      float a1[2][4] = {};
      for (int j = 0; j < 64; ++j) {
        float s0 = Sc[i0][j], s1 = Sc[i0 + 1][j];
        float x0 = Xs[j][p0], x1 = Xs[j][p0 + 1], x2 = Xs[j][p0 + 2], x3 = Xs[j][p0 + 3];
        a1[0][0] += s0 * x0; a1[0][1] += s0 * x1; a1[0][2] += s0 * x2; a1[0][3] += s0 * x3;
        a1[1][0] += s1 * x0; a1[1][1] += s1 * x1; a1[1][2] += s1 * x2; a1[1][3] += s1 * x3;
      }
      float a2[2][4] = {};
      for (int n = 0; n < 128; ++n) {
        float c0 = Cs[i0][n], c1 = Cs[i0 + 1][n];
        float t0 = st[p0][n], t1 = st[p0 + 1][n], t2 = st[p0 + 2][n], t3 = st[p0 + 3][n];
        a2[0][0] += c0 * t0; a2[0][1] += c0 * t1; a2[0][2] += c0 * t2; a2[0][3] += c0 * t3;
        a2[1][0] += c1 * t0; a2[1][1] += c1 * t1; a2[1][2] += c1 * t2; a2[1][3] += c1 * t3;
      }
      float e0 = expf(cs[i0]), e1 = expf(cs[i0 + 1]);
#pragma unroll
      for (int ii = 0; ii < 2; ++ii) {
        const long r = rowbase + i0 + ii;
        const long zo = r * 4096 + h * 64 + p0;
        const unsigned short* xr = proj + r * PROJ_N + h * 64 + p0;
        float e = ii ? e1 : e0;
#pragma unroll
        for (int pp = 0; pp < 4; ++pp) {
          float y = a1[ii][pp] + e * a2[ii][pp];
          float xraw = bf2f(xr[pp]);
          float zz = bf2f(zio[zo + pp]);
          float sz = zz / (1.f + expf(-zz));
          zio[zo + pp] = f2bf((y + xraw * Dh) * sz);
        }
      }
    }
    __syncthreads();
    {
      const int j = tid >> 3;
      const int p0 = (tid & 7) * 8;
      float f = expf(cs[63] - cs[j]);
#pragma unroll
      for (int q = 0; q < 8; ++q) Xs[j][p0 + q] *= f;
    }
    __syncthreads();
    {
      const float dec = expf(cs[63]);
      const int p0 = (tid >> 5) * 4;
      const int n0 = (tid & 31) * 4;
      float a[4][4] = {};
      for (int j = 0; j < 64; ++j) {
        float x0 = Xs[j][p0], x1 = Xs[j][p0 + 1], x2 = Xs[j][p0 + 2], x3 = Xs[j][p0 + 3];
        float b0 = Bs[j][n0], b1 = Bs[j][n0 + 1], b2 = Bs[j][n0 + 2], b3 = Bs[j][n0 + 3];
        a[0][0] += x0 * b0; a[0][1] += x0 * b1; a[0][2] += x0 * b2; a[0][3] += x0 * b3;
        a[1][0] += x1 * b0; a[1][1] += x1 * b1; a[1][2] += x1 * b2; a[1][3] += x1 * b3;
        a[2][0] += x2 * b0; a[2][1] += x2 * b1; a[2][2] += x2 * b2; a[2][3] += x2 * b3;
        a[3][0] += x3 * b0; a[3][1] += x3 * b1; a[3][2] += x3 * b2; a[3][3] += x3 * b3;
      }
#pragma unroll
      for (int pp = 0; pp < 4; ++pp)
#pragma unroll
        for (int nn = 0; nn < 4; ++nn)
          st[p0 + pp][n0 + nn] = dec * st[p0 + pp][n0 + nn] + a[pp][nn];
    }
    __syncthreads();
  }
}

// ---------- launch ----------
extern "C" void kernel_launch(void* const* d_in, const int* in_sizes, int n_in,
                              void* d_out, int out_size, void* d_ws, size_t ws_size,
                              hipStream_t stream) {
  (void)in_sizes; (void)n_in; (void)out_size;
  const float* x    = (const float*)d_in[0];
  const float* w1   = (const float*)d_in[1]; // 8192 x 2048
  const float* cw   = (const float*)d_in[2]; // 4096 x 4
  const float* cb   = (const float*)d_in[3]; // 4096
  const float* w2   = (const float*)d_in[4]; // 4416 x 4096
  const float* dtw  = (const float*)d_in[5]; // 64 x 64
  const float* dtb  = (const float*)d_in[6]; // 64
  const float* Alog = (const float*)d_in[7]; // 64
  const float* Dv   = (const float*)d_in[8]; // 64
  const float* w3   = (const float*)d_in[9]; // 2048 x 4096
  float* out = (float*)d_out;

  const size_t NEED8 = 410025984ull;   // CR=8192 new path
  const size_t NEED4 = 205012992ull;   // CR=4096 new path
  int CR; bool newpath;
  if      (ws_size >= NEED8)               { CR = 8192; newpath = true;  }
  else if (ws_size >= NEED4)               { CR = 4096; newpath = true;  }
  else if (ws_size >= (size_t)8192 * 17280){ CR = 8192; newpath = false; }
  else if (ws_size >= (size_t)4096 * 17280){ CR = 4096; newpath = false; }
  else return;  // diagnostic: error == 8.69e-2 means ws too small

  char* w = (char*)d_ws;
  const size_t S1 = (size_t)CR * 4096 * 2;
  const size_t S2 = (size_t)CR * PROJ_N * 2;
  const int nb = CR / LSEQ;
  unsigned short* xc   = (unsigned short*)(w);       // conv out   [0, S1)
  unsigned short* xp   = (unsigned short*)(w + S1);  // pre-conv   (inside proj region)
  unsigned short* proj = (unsigned short*)(w + S1);  // x_proj out — over xp (dead)
  unsigned short* z    = (unsigned short*)(w);       // z branch — over xc (dead)
  float* dtf           = (float*)(w + S1 + S2);
  float* chdec         = (float*)(w + S1 + S2 + (size_t)CR * 256);
  float* states        = (float*)(w + S1 + S2 + (size_t)CR * 256 + (size_t)nb * 16384);

  // bf16 operand staging (inside states region — dead before ssd_states writes it)
  unsigned short* xbf  = (unsigned short*)states;            // CR x 2048
  unsigned short* w1bf = xbf + (size_t)CR * 2048;            // 8192 x 2048
  unsigned short* w2bf = w1bf + (size_t)8192 * 2048;         // 4416 x 4096
  unsigned short* w3bf = (unsigned short*)states;            // 2048 x 4096 (after ssd)

  for (int r0 = 0; r0 < 8192; r0 += CR) {
    const float* xr = x + (size_t)r0 * DMODEL;
    if (newpath) {
      dim3 G1(DINNER / 256, CR / 256);            // 16 x 32
      dim3 G2(18, CR / 256);                      // ceil(4416/256)=18 (rows clamped)
      dim3 G3(DMODEL / 256, CR / 256);            // 8 x 32
      // 0) convert x, w1, w2 to bf16 (RNE)
      f2bf_kernel<<<((long)CR * 2048 / 8 + 255) / 256, 256, 0, stream>>>(xr, xbf, (long)CR * 2048 / 8);
      f2bf_kernel<<<((long)8192 * 2048 / 8 + 255) / 256, 256, 0, stream>>>(w1, w1bf, (long)8192 * 2048 / 8);
      f2bf_kernel<<<((long)4416 * 4096 / 8 + 255) / 256, 256, 0, stream>>>(w2, w2bf, (long)4416 * 4096 / 8);
      // 1) in_proj x-half -> xp
      gemm256<0><<<G1, 512, 0, stream>>>(xbf, w1bf, xp, DMODEL, DINNER, DINNER);
      // 2) conv + silu -> xc
      conv_silu_kernel<<<((long)CR * 512) / 256, 256, 0, stream>>>(xp, cw, cb, xc, (long)CR * 512);
      // 3) x_proj -> proj
      gemm256<0><<<G2, 512, 0, stream>>>(xc, w2bf, proj, DINNER, PROJ_N, PROJ_N);
      // 4) dt
      dt_kernel<<<((long)CR * NHEADS) / 256, 256, 0, stream>>>(proj, dtw, dtb, dtf, (long)CR * NHEADS);
      // 5) in_proj z-half -> z
      gemm256<0><<<G1, 512, 0, stream>>>(xbf, w1bf + (size_t)DINNER * DMODEL, z, DMODEL, DINNER, DINNER);
      // 6) SSD + gate (states region overwrites xbf/w1bf/w2bf — all dead now)
      ssd_states_kernel<<<dim3(nb * 64, 64), 256, 0, stream>>>(proj, dtf, Alog, states, chdec);
      ssd_scan_kernel<<<dim3(32, nb * 64), 256, 0, stream>>>(states, chdec);
      ssd_ydo_gate_kernel<<<dim3(nb * 64, 4), 512, 0, stream>>>(proj, dtf, Alog, Dv, states, z);
      // 7) out_proj (w3 converted after states is dead, into states region)
      f2bf_kernel<<<((long)2048 * 4096 / 8 + 255) / 256, 256, 0, stream>>>(w3, w3bf, (long)2048 * 4096 / 8);
      gemm256<1><<<G3, 512, 0, stream>>>(z, w3bf, out + (size_t)r0 * DMODEL, DINNER, DMODEL, DMODEL);
    } else {
      dim3 g1(DINNER / 128, CR / 128);
      dim3 g2((PROJ_N + 127) / 128, CR / 128);
      dim3 g3(DMODEL / 128, CR / 128);
      gemm_nt<true, true><<<g1, 256, 0, stream>>>(xr, w1, xp, DMODEL, DINNER, DINNER);
      conv_silu_kernel<<<((long)CR * 512) / 256, 256, 0, stream>>>(xp, cw, cb, xc, (long)CR * 512);
      gemm_nt<false, true><<<g2, 256, 0, stream>>>(xc, w2, proj, DINNER, PROJ_N, PROJ_N);
      dt_kernel<<<((long)CR * NHEADS) / 256, 256, 0, stream>>>(proj, dtw, dtb, dtf, (long)CR * NHEADS);
      gemm_nt<true, true><<<g1, 256, 0, stream>>>(xr, w1 + (size_t)DINNER * DMODEL, z, DMODEL, DINNER, DINNER);
      ssd_gate_kernel<<<(CR / LSEQ) * NHEADS, 512, 0, stream>>>(proj, dtf, Alog, Dv, z);
      gemm_nt<false, false><<<g3, 256, 0, stream>>>(z, w3, out + (size_t)r0 * DMODEL, DINNER, DMODEL, DMODEL);
    }
  }
}